// Round 1
// baseline (762.787 us; speedup 1.0000x reference)
//
#include <hip/hip_runtime.h>
#include <math.h>

#define TOTAL_Q   2048
#define TOTAL_KV  2048
#define QIN       1024
#define KVIN      1033
#define DQK       1024
#define DV        1024
#define NHEADS    16
#define SCALER    0.125f   // 1/sqrt(64)

// ---------------------------------------------------------------------------
// Generic fp32 tiled GEMM:  C[M,N] = A[M,K] @ W[K,N] + bias[N]
// 64x64 block tile, BK=16, 256 threads, 4x4 micro-tile per thread.
// K may be non-multiple of BK (K=1033 for the K/V projections) -> edge guard.
// ---------------------------------------------------------------------------
#define BM 64
#define BN 64
#define BK 16

__global__ __launch_bounds__(256)
void gemm_bias(const float* __restrict__ A, const float* __restrict__ W,
               const float* __restrict__ bias, float* __restrict__ C,
               int M, int N, int K)
{
    __shared__ float As[BK][BM + 1];   // +1 pad: avoid bank conflicts on transposed store
    __shared__ float Ws[BK][BN];

    const int tid  = threadIdx.x;
    const int tx   = tid & 15;
    const int ty   = tid >> 4;
    const int row0 = blockIdx.y * BM;
    const int col0 = blockIdx.x * BN;

    float acc[4][4] = {};

    for (int k0 = 0; k0 < K; k0 += BK) {
        // A tile: 64 rows x 16 k (1024 elems, 4 per thread).
        // consecutive tid -> consecutive k within a row (coalesced 16-float runs)
        {
            int t = tid;
            #pragma unroll
            for (int it = 0; it < (BM * BK) / 256; ++it, t += 256) {
                int r  = t >> 4;
                int kk = t & 15;
                int kg = k0 + kk;
                As[kk][r] = (kg < K) ? A[(size_t)(row0 + r) * K + kg] : 0.f;
            }
        }
        // W tile: 16 k x 64 cols. consecutive tid -> consecutive col (coalesced)
        {
            int t = tid;
            #pragma unroll
            for (int it = 0; it < (BK * BN) / 256; ++it, t += 256) {
                int kk = t >> 6;
                int c  = t & 63;
                int kg = k0 + kk;
                Ws[kk][c] = (kg < K) ? W[(size_t)kg * N + col0 + c] : 0.f;
            }
        }
        __syncthreads();

        #pragma unroll
        for (int kk = 0; kk < BK; ++kk) {
            float a[4], b[4];
            #pragma unroll
            for (int m = 0; m < 4; ++m) a[m] = As[kk][ty * 4 + m];
            #pragma unroll
            for (int n = 0; n < 4; ++n) b[n] = Ws[kk][tx * 4 + n];
            #pragma unroll
            for (int m = 0; m < 4; ++m)
                #pragma unroll
                for (int n = 0; n < 4; ++n)
                    acc[m][n] += a[m] * b[n];
        }
        __syncthreads();
    }

    #pragma unroll
    for (int m = 0; m < 4; ++m) {
        int r = row0 + ty * 4 + m;
        #pragma unroll
        for (int n = 0; n < 4; ++n) {
            int c = col0 + tx * 4 + n;
            C[(size_t)r * N + c] = acc[m][n] + bias[c];
        }
    }
}

// ---------------------------------------------------------------------------
// Segmented attention.
// One block (256 threads = 4 waves) per query row. Wave w owns heads
// 4w..4w+3; within the wave, lanes [16g, 16g+16) own head 4w+g, each lane
// holding a float4 slice of the 64-wide head dim. Online softmax streams
// the segment's kv rows; dot-product reduced over the 16-lane subgroup via
// __shfl_xor (masks 1,2,4,8 stay inside the aligned 16-group).
// seg_kv is sorted (repeat of arange) -> binary search for segment bounds.
// ---------------------------------------------------------------------------
__global__ __launch_bounds__(256)
void attn_kernel(const float* __restrict__ q, const float* __restrict__ k,
                 const float* __restrict__ v, const int* __restrict__ seg_q,
                 const int* __restrict__ seg_kv, float* __restrict__ wv)
{
    const int i = blockIdx.x;  // query row
    __shared__ int sb[2];
    if (threadIdx.x == 0) {
        int s = seg_q[i];
        int lo = 0, hi = TOTAL_KV;
        while (lo < hi) { int mid = (lo + hi) >> 1; if (seg_kv[mid] <  s) lo = mid + 1; else hi = mid; }
        sb[0] = lo;
        int lo2 = lo, hi2 = TOTAL_KV;
        while (lo2 < hi2) { int mid = (lo2 + hi2) >> 1; if (seg_kv[mid] <= s) lo2 = mid + 1; else hi2 = mid; }
        sb[1] = lo2;
    }
    __syncthreads();
    const int jbeg = sb[0], jend = sb[1];

    const int wave = threadIdx.x >> 6;
    const int lane = threadIdx.x & 63;
    const int col  = wave * 256 + lane * 4;   // feature offset in [0,1024)

    const float4 q4 = *(const float4*)(q + (size_t)i * DQK + col);

    float m_run = -1e30f, l_run = 0.f;
    float4 acc = {0.f, 0.f, 0.f, 0.f};

    for (int j = jbeg; j < jend; ++j) {
        const float4 k4 = *(const float4*)(k + (size_t)j * DQK + col);
        float p = q4.x * k4.x + q4.y * k4.y + q4.z * k4.z + q4.w * k4.w;
        p += __shfl_xor(p, 1);
        p += __shfl_xor(p, 2);
        p += __shfl_xor(p, 4);
        p += __shfl_xor(p, 8);
        const float score = p * SCALER;

        const float m_new = fmaxf(m_run, score);
        const float alpha = __expf(m_run - m_new);
        const float pexp  = __expf(score - m_new);

        const float4 v4 = *(const float4*)(v + (size_t)j * DV + col);
        acc.x = acc.x * alpha + pexp * v4.x;
        acc.y = acc.y * alpha + pexp * v4.y;
        acc.z = acc.z * alpha + pexp * v4.z;
        acc.w = acc.w * alpha + pexp * v4.w;
        l_run = l_run * alpha + pexp;
        m_run = m_new;
    }

    const float inv = 1.f / l_run;
    float4 o;
    o.x = acc.x * inv; o.y = acc.y * inv; o.z = acc.z * inv; o.w = acc.w * inv;
    *(float4*)(wv + (size_t)i * DV + col) = o;
}

// ---------------------------------------------------------------------------
extern "C" void kernel_launch(void* const* d_in, const int* in_sizes, int n_in,
                              void* d_out, int out_size, void* d_ws, size_t ws_size,
                              hipStream_t stream)
{
    const float* A     = (const float*)d_in[0];
    const float* B0    = (const float*)d_in[1];
    const int*   seg_q = (const int*)  d_in[2];
    const int*   seg_kv= (const int*)  d_in[3];
    const float* Wq    = (const float*)d_in[4];
    const float* bq    = (const float*)d_in[5];
    const float* Wk    = (const float*)d_in[6];
    const float* bk    = (const float*)d_in[7];
    const float* Wv    = (const float*)d_in[8];
    const float* bv    = (const float*)d_in[9];
    const float* Wf    = (const float*)d_in[10];
    const float* bf    = (const float*)d_in[11];
    float* out = (float*)d_out;

    float* q  = (float*)d_ws;                 // 2048*1024 fp32 = 8 MB
    float* k  = q  + (size_t)TOTAL_KV * DQK;  // 8 MB
    float* v  = k  + (size_t)TOTAL_KV * DQK;  // 8 MB
    float* wv = v  + (size_t)TOTAL_KV * DV;   // 8 MB   (total 32 MB of d_ws)

    const dim3 blk(256);
    const dim3 gg(DQK / BN, TOTAL_Q / BM);    // (16, 32)

    gemm_bias<<<gg, blk, 0, stream>>>(A,  Wq, bq, q,  TOTAL_Q,  DQK, QIN);
    gemm_bias<<<gg, blk, 0, stream>>>(B0, Wk, bk, k,  TOTAL_KV, DQK, KVIN);
    gemm_bias<<<gg, blk, 0, stream>>>(B0, Wv, bv, v,  TOTAL_KV, DV,  KVIN);

    attn_kernel<<<dim3(TOTAL_Q), blk, 0, stream>>>(q, k, v, seg_q, seg_kv, wv);

    gemm_bias<<<gg, blk, 0, stream>>>(wv, Wf, bf, out, TOTAL_Q, QIN, DV);
}

// Round 2
// 230.205 us; speedup vs baseline: 3.3135x; 3.3135x over previous
//
#include <hip/hip_runtime.h>
#include <hip/hip_bf16.h>
#include <math.h>

#define TOTAL_Q   2048
#define TOTAL_KV  2048
#define QIN       1024
#define KVIN      1033
#define KVIN_P    1056      // KVIN padded to multiple of 32 (zero-filled)
#define DQK       1024
#define DV        1024
#define SCALER    0.125f    // 1/sqrt(64)

typedef __bf16 bf16x8 __attribute__((ext_vector_type(8)));
typedef float  f32x4  __attribute__((ext_vector_type(4)));

// ---------------------------------------------------------------------------
// fp32 -> bf16 cast (n multiple of 4)
// ---------------------------------------------------------------------------
__global__ __launch_bounds__(256)
void cast_bf16_k(const float* __restrict__ in, __hip_bfloat16* __restrict__ out, int n)
{
    int i = (blockIdx.x * 256 + threadIdx.x) * 4;
    if (i >= n) return;
    float4 f = *(const float4*)(in + i);
    __hip_bfloat16 o[4] = { __float2bfloat16(f.x), __float2bfloat16(f.y),
                            __float2bfloat16(f.z), __float2bfloat16(f.w) };
    *(uint2*)(out + i) = *(const uint2*)o;
}

// fp32 [2048][1033] -> bf16 [2048][1056], cols >= 1033 zero-filled
__global__ __launch_bounds__(256)
void cast_pad_k(const float* __restrict__ in, __hip_bfloat16* __restrict__ out)
{
    int idx = blockIdx.x * 256 + threadIdx.x;
    if (idx >= TOTAL_KV * KVIN_P) return;
    int r = idx / KVIN_P, c = idx - r * KVIN_P;
    float v = (c < KVIN) ? in[(size_t)r * KVIN + c] : 0.f;
    out[idx] = __float2bfloat16(v);
}

// W[K][1024] fp32 -> Wt[1024][Kp] bf16 (transposed, k >= K zero-filled)
__global__ __launch_bounds__(256)
void transpose_cast_k(const float* __restrict__ W, __hip_bfloat16* __restrict__ Wt,
                      int K, int Kp)
{
    __shared__ float tile[32][33];
    const int k0 = blockIdx.x * 32, n0 = blockIdx.y * 32;
    #pragma unroll
    for (int i = 0; i < 4; ++i) {
        int k = k0 + threadIdx.y + i * 8;
        tile[threadIdx.y + i * 8][threadIdx.x] =
            (k < K) ? W[(size_t)k * 1024 + n0 + threadIdx.x] : 0.f;
    }
    __syncthreads();
    #pragma unroll
    for (int i = 0; i < 4; ++i) {
        int n = n0 + threadIdx.y + i * 8;
        Wt[(size_t)n * Kp + k0 + threadIdx.x] =
            __float2bfloat16(tile[threadIdx.x][threadIdx.y + i * 8]);
    }
}

// ---------------------------------------------------------------------------
// bf16 MFMA GEMM:  C[M,N] = A[M,K] @ Bt[N,K]^T + bias[N]
// 64x64 tile, BK=32, 256 threads = 4 waves (2x2), each wave 32x32 (2x2 MFMAs
// of 16x16x32). LDS rows padded to 40 elems (80 B = 20-bank shift, 16B-aligned
// fragment reads, only free 2-way conflicts).
// A-frag: A[m=lane&15][k=quad*8+j]; B-frag: B[k=quad*8+j][n=lane&15];
// C/D: col=lane&15, row=quad*4+reg  (guide-verified layouts).
// ---------------------------------------------------------------------------
template<int OUT_BF16>
__global__ __launch_bounds__(256)
void gemm_mfma(const __hip_bfloat16* __restrict__ A,
               const __hip_bfloat16* __restrict__ Bt,
               const float* __restrict__ bias,
               void* __restrict__ Cv,
               int M, int N, int K)
{
    __shared__ __bf16 As[64][40];
    __shared__ __bf16 Bs[64][40];

    const int tid  = threadIdx.x;
    const int wave = tid >> 6, lane = tid & 63;
    const int quad = lane >> 4, l16 = lane & 15;
    const int wm = (wave >> 1) * 32, wn = (wave & 1) * 32;
    const int row0 = blockIdx.y * 64, col0 = blockIdx.x * 64;

    const int sr = tid >> 2;            // staging row (A) / n (B): 0..63
    const int sk = (tid & 3) * 8;       // staging k offset

    const __hip_bfloat16* Ag = A  + (size_t)(row0 + sr) * K + sk;
    const __hip_bfloat16* Bg = Bt + (size_t)(col0 + sr) * K + sk;

    f32x4 acc[2][2] = {};

    for (int k0 = 0; k0 < K; k0 += 32) {
        *(bf16x8*)&As[sr][sk] = *(const bf16x8*)(Ag + k0);
        *(bf16x8*)&Bs[sr][sk] = *(const bf16x8*)(Bg + k0);
        __syncthreads();

        bf16x8 af[2], bfq[2];
        #pragma unroll
        for (int mi = 0; mi < 2; ++mi)
            af[mi] = *(const bf16x8*)&As[wm + mi * 16 + l16][quad * 8];
        #pragma unroll
        for (int ni = 0; ni < 2; ++ni)
            bfq[ni] = *(const bf16x8*)&Bs[wn + ni * 16 + l16][quad * 8];

        #pragma unroll
        for (int mi = 0; mi < 2; ++mi)
            #pragma unroll
            for (int ni = 0; ni < 2; ++ni)
                acc[mi][ni] = __builtin_amdgcn_mfma_f32_16x16x32_bf16(
                    af[mi], bfq[ni], acc[mi][ni], 0, 0, 0);
        __syncthreads();
    }

    #pragma unroll
    for (int mi = 0; mi < 2; ++mi) {
        #pragma unroll
        for (int ni = 0; ni < 2; ++ni) {
            const int col = col0 + wn + ni * 16 + l16;
            const float b = bias[col];
            #pragma unroll
            for (int r = 0; r < 4; ++r) {
                const int row = row0 + wm + mi * 16 + quad * 4 + r;
                const float val = acc[mi][ni][r] + b;
                if (OUT_BF16)
                    ((__hip_bfloat16*)Cv)[(size_t)row * N + col] = __float2bfloat16(val);
                else
                    ((float*)Cv)[(size_t)row * N + col] = val;
            }
        }
    }
}

// ---------------------------------------------------------------------------
// Segmented attention, bf16 q/k/v/out, fp32 math.
// One block per query row; 16 lanes per head, 4 bf16 features per lane.
// ---------------------------------------------------------------------------
__device__ __forceinline__ float bfu(unsigned u) { return __uint_as_float(u << 16); }

__global__ __launch_bounds__(256)
void attn_kernel(const __hip_bfloat16* __restrict__ q,
                 const __hip_bfloat16* __restrict__ k,
                 const __hip_bfloat16* __restrict__ v,
                 const int* __restrict__ seg_q, const int* __restrict__ seg_kv,
                 __hip_bfloat16* __restrict__ wv)
{
    const int i = blockIdx.x;
    __shared__ int sb[2];
    if (threadIdx.x == 0) {
        int s = seg_q[i];
        int lo = 0, hi = TOTAL_KV;
        while (lo < hi) { int mid = (lo + hi) >> 1; if (seg_kv[mid] <  s) lo = mid + 1; else hi = mid; }
        sb[0] = lo;
        int lo2 = lo, hi2 = TOTAL_KV;
        while (lo2 < hi2) { int mid = (lo2 + hi2) >> 1; if (seg_kv[mid] <= s) lo2 = mid + 1; else hi2 = mid; }
        sb[1] = lo2;
    }
    __syncthreads();
    const int jbeg = sb[0], jend = sb[1];

    const int wave = threadIdx.x >> 6;
    const int lane = threadIdx.x & 63;
    const int col  = wave * 256 + lane * 4;

    uint2 qr = *(const uint2*)(q + (size_t)i * DQK + col);
    const float q0 = bfu(qr.x & 0xffffu), q1 = bfu(qr.x >> 16);
    const float q2 = bfu(qr.y & 0xffffu), q3 = bfu(qr.y >> 16);

    float m_run = -1e30f, l_run = 0.f;
    float a0 = 0.f, a1 = 0.f, a2 = 0.f, a3 = 0.f;

    for (int j = jbeg; j < jend; ++j) {
        uint2 kr = *(const uint2*)(k + (size_t)j * DQK + col);
        float p = q0 * bfu(kr.x & 0xffffu) + q1 * bfu(kr.x >> 16)
                + q2 * bfu(kr.y & 0xffffu) + q3 * bfu(kr.y >> 16);
        p += __shfl_xor(p, 1);
        p += __shfl_xor(p, 2);
        p += __shfl_xor(p, 4);
        p += __shfl_xor(p, 8);
        const float score = p * SCALER;

        const float m_new = fmaxf(m_run, score);
        const float alpha = __expf(m_run - m_new);
        const float pexp  = __expf(score - m_new);

        uint2 vr = *(const uint2*)(v + (size_t)j * DV + col);
        a0 = a0 * alpha + pexp * bfu(vr.x & 0xffffu);
        a1 = a1 * alpha + pexp * bfu(vr.x >> 16);
        a2 = a2 * alpha + pexp * bfu(vr.y & 0xffffu);
        a3 = a3 * alpha + pexp * bfu(vr.y >> 16);
        l_run = l_run * alpha + pexp;
        m_run = m_new;
    }

    const float inv = 1.f / l_run;
    __hip_bfloat16 o[4] = { __float2bfloat16(a0 * inv), __float2bfloat16(a1 * inv),
                            __float2bfloat16(a2 * inv), __float2bfloat16(a3 * inv) };
    *(uint2*)(wv + (size_t)i * DV + col) = *(const uint2*)o;
}

// ---------------------------------------------------------------------------
extern "C" void kernel_launch(void* const* d_in, const int* in_sizes, int n_in,
                              void* d_out, int out_size, void* d_ws, size_t ws_size,
                              hipStream_t stream)
{
    const float* A     = (const float*)d_in[0];
    const float* B0    = (const float*)d_in[1];
    const int*   seg_q = (const int*)  d_in[2];
    const int*   seg_kv= (const int*)  d_in[3];
    const float* Wq    = (const float*)d_in[4];
    const float* bq    = (const float*)d_in[5];
    const float* Wk    = (const float*)d_in[6];
    const float* bk    = (const float*)d_in[7];
    const float* Wv    = (const float*)d_in[8];
    const float* bv    = (const float*)d_in[9];
    const float* Wf    = (const float*)d_in[10];
    const float* bf    = (const float*)d_in[11];
    float* out = (float*)d_out;

    // Workspace layout (bf16 elements), total 29.6 MB
    __hip_bfloat16* B0bf = (__hip_bfloat16*)d_ws;                 // 2048*1056
    __hip_bfloat16* Wqt  = B0bf + (size_t)TOTAL_KV * KVIN_P;      // 1024*1024
    __hip_bfloat16* Wkt  = Wqt  + (size_t)QIN * DQK;              // 1024*1056
    __hip_bfloat16* Wvt  = Wkt  + (size_t)DQK * KVIN_P;           // 1024*1056
    __hip_bfloat16* Wft  = Wvt  + (size_t)DV * KVIN_P;            // 1024*1024
    __hip_bfloat16* Abf  = Wft  + (size_t)DV * QIN;               // 2048*1024
    __hip_bfloat16* qb   = Abf  + (size_t)TOTAL_Q * QIN;          // 2048*1024
    __hip_bfloat16* kb   = qb   + (size_t)TOTAL_Q * DQK;          // 2048*1024
    __hip_bfloat16* vb   = kb   + (size_t)TOTAL_KV * DQK;         // 2048*1024
    __hip_bfloat16* wvb  = Abf;  // alias: Abf dead after q-projection

    const dim3 b256(256);

    // Casts / transposes
    cast_bf16_k<<<dim3((TOTAL_Q * QIN / 4 + 255) / 256), b256, 0, stream>>>(A, Abf, TOTAL_Q * QIN);
    cast_pad_k<<<dim3((TOTAL_KV * KVIN_P + 255) / 256), b256, 0, stream>>>(B0, B0bf);
    transpose_cast_k<<<dim3(DQK / 32, QIN / 32), dim3(32, 8), 0, stream>>>(Wq, Wqt, QIN,  DQK);
    transpose_cast_k<<<dim3(KVIN_P / 32, DQK / 32), dim3(32, 8), 0, stream>>>(Wk, Wkt, KVIN, KVIN_P);
    transpose_cast_k<<<dim3(KVIN_P / 32, DV  / 32), dim3(32, 8), 0, stream>>>(Wv, Wvt, KVIN, KVIN_P);
    transpose_cast_k<<<dim3(DV / 32, QIN / 32), dim3(32, 8), 0, stream>>>(Wf, Wft, DV, QIN);

    // Projections (bf16 out)
    const dim3 gg(DQK / 64, TOTAL_Q / 64);   // (16, 32) = 512 blocks
    gemm_mfma<1><<<gg, b256, 0, stream>>>(Abf,  Wqt, bq, qb, TOTAL_Q,  DQK, QIN);
    gemm_mfma<1><<<gg, b256, 0, stream>>>(B0bf, Wkt, bk, kb, TOTAL_KV, DQK, KVIN_P);
    gemm_mfma<1><<<gg, b256, 0, stream>>>(B0bf, Wvt, bv, vb, TOTAL_KV, DV,  KVIN_P);

    // Attention
    attn_kernel<<<dim3(TOTAL_Q), b256, 0, stream>>>(qb, kb, vb, seg_q, seg_kv, wvb);

    // Output projection (fp32 out)
    gemm_mfma<0><<<gg, b256, 0, stream>>>(wvb, Wft, bf, out, TOTAL_Q, QIN, DV);
}

// Round 3
// 203.017 us; speedup vs baseline: 3.7573x; 1.1339x over previous
//
#include <hip/hip_runtime.h>
#include <hip/hip_bf16.h>
#include <math.h>

#define TOTAL_Q   2048
#define TOTAL_KV  2048
#define QIN       1024
#define KVIN      1033
#define KVIN_P    1056      // KVIN padded to multiple of 32 (zero-filled)
#define DQK       1024
#define DV        1024
#define SCALER    0.125f    // 1/sqrt(64)

typedef __bf16 bf16x8 __attribute__((ext_vector_type(8)));
typedef float  f32x4  __attribute__((ext_vector_type(4)));

// ---------------------------------------------------------------------------
// fp32 -> bf16 cast (n multiple of 4)
// ---------------------------------------------------------------------------
__global__ __launch_bounds__(256)
void cast_bf16_k(const float* __restrict__ in, __hip_bfloat16* __restrict__ out, int n)
{
    int i = (blockIdx.x * 256 + threadIdx.x) * 4;
    if (i >= n) return;
    float4 f = *(const float4*)(in + i);
    __hip_bfloat16 o[4] = { __float2bfloat16(f.x), __float2bfloat16(f.y),
                            __float2bfloat16(f.z), __float2bfloat16(f.w) };
    *(uint2*)(out + i) = *(const uint2*)o;
}

// fp32 [2048][1033] -> bf16 [2048][1056], cols >= 1033 zero-filled
__global__ __launch_bounds__(256)
void cast_pad_k(const float* __restrict__ in, __hip_bfloat16* __restrict__ out)
{
    int idx = blockIdx.x * 256 + threadIdx.x;
    if (idx >= TOTAL_KV * KVIN_P) return;
    int r = idx / KVIN_P, c = idx - r * KVIN_P;
    float v = (c < KVIN) ? in[(size_t)r * KVIN + c] : 0.f;
    out[idx] = __float2bfloat16(v);
}

// W[K][1024] fp32 -> Wt[1024][Kp] bf16 (transposed, k >= K zero-filled)
__global__ __launch_bounds__(256)
void transpose_cast_k(const float* __restrict__ W, __hip_bfloat16* __restrict__ Wt,
                      int K, int Kp)
{
    __shared__ float tile[32][33];
    const int k0 = blockIdx.x * 32, n0 = blockIdx.y * 32;
    #pragma unroll
    for (int i = 0; i < 4; ++i) {
        int k = k0 + threadIdx.y + i * 8;
        tile[threadIdx.y + i * 8][threadIdx.x] =
            (k < K) ? W[(size_t)k * 1024 + n0 + threadIdx.x] : 0.f;
    }
    __syncthreads();
    #pragma unroll
    for (int i = 0; i < 4; ++i) {
        int n = n0 + threadIdx.y + i * 8;
        Wt[(size_t)n * Kp + k0 + threadIdx.x] =
            __float2bfloat16(tile[threadIdx.x][threadIdx.y + i * 8]);
    }
}

// ---------------------------------------------------------------------------
// bf16 MFMA GEMM:  C[M,N] = A[M,K] @ Bt[N,K]^T + bias[N]   (unchanged from R1)
// ---------------------------------------------------------------------------
template<int OUT_BF16>
__global__ __launch_bounds__(256)
void gemm_mfma(const __hip_bfloat16* __restrict__ A,
               const __hip_bfloat16* __restrict__ Bt,
               const float* __restrict__ bias,
               void* __restrict__ Cv,
               int M, int N, int K)
{
    __shared__ __bf16 As[64][40];
    __shared__ __bf16 Bs[64][40];

    const int tid  = threadIdx.x;
    const int wave = tid >> 6, lane = tid & 63;
    const int quad = lane >> 4, l16 = lane & 15;
    const int wm = (wave >> 1) * 32, wn = (wave & 1) * 32;
    const int row0 = blockIdx.y * 64, col0 = blockIdx.x * 64;

    const int sr = tid >> 2;
    const int sk = (tid & 3) * 8;

    const __hip_bfloat16* Ag = A  + (size_t)(row0 + sr) * K + sk;
    const __hip_bfloat16* Bg = Bt + (size_t)(col0 + sr) * K + sk;

    f32x4 acc[2][2] = {};

    for (int k0 = 0; k0 < K; k0 += 32) {
        *(bf16x8*)&As[sr][sk] = *(const bf16x8*)(Ag + k0);
        *(bf16x8*)&Bs[sr][sk] = *(const bf16x8*)(Bg + k0);
        __syncthreads();

        bf16x8 af[2], bfq[2];
        #pragma unroll
        for (int mi = 0; mi < 2; ++mi)
            af[mi] = *(const bf16x8*)&As[wm + mi * 16 + l16][quad * 8];
        #pragma unroll
        for (int ni = 0; ni < 2; ++ni)
            bfq[ni] = *(const bf16x8*)&Bs[wn + ni * 16 + l16][quad * 8];

        #pragma unroll
        for (int mi = 0; mi < 2; ++mi)
            #pragma unroll
            for (int ni = 0; ni < 2; ++ni)
                acc[mi][ni] = __builtin_amdgcn_mfma_f32_16x16x32_bf16(
                    af[mi], bfq[ni], acc[mi][ni], 0, 0, 0);
        __syncthreads();
    }

    #pragma unroll
    for (int mi = 0; mi < 2; ++mi) {
        #pragma unroll
        for (int ni = 0; ni < 2; ++ni) {
            const int col = col0 + wn + ni * 16 + l16;
            const float b = bias[col];
            #pragma unroll
            for (int r = 0; r < 4; ++r) {
                const int row = row0 + wm + mi * 16 + quad * 4 + r;
                const float val = acc[mi][ni][r] + b;
                if (OUT_BF16)
                    ((__hip_bfloat16*)Cv)[(size_t)row * N + col] = __float2bfloat16(val);
                else
                    ((float*)Cv)[(size_t)row * N + col] = val;
            }
        }
    }
}

// ---------------------------------------------------------------------------
// MFMA flash attention over ragged segments.
// Block = (segment s, head h): blockIdx.x = s*16 + h. 256 threads = 4 waves.
// q-tiles of 64 rows (wave w owns 16), kv chunks of CH=64 through LDS.
// S = q@k^T per 16x16 tile (mfma_16x16x32, K-loop over d=64), online softmax
// in C-layout regs (shfl within quad's 16-lane group), P -> LDS (bf16, A-layout),
// O += P@V with V transposed in LDS.
// Layouts (guide-verified, same as gemm_mfma):
//   A-frag A[m=l16][k=quad*8+j], B-frag B[k=quad*8+j][n=l16],
//   C/D    col=l16, row=quad*4+r.
// ---------------------------------------------------------------------------
#define CH 64

__global__ __launch_bounds__(256)
void attn_mfma(const __hip_bfloat16* __restrict__ qg,
               const __hip_bfloat16* __restrict__ kg,
               const __hip_bfloat16* __restrict__ vg,
               const int* __restrict__ seg_q, const int* __restrict__ seg_kv,
               __hip_bfloat16* __restrict__ wv)
{
    const int h = blockIdx.x & 15;
    const int s = blockIdx.x >> 4;

    __shared__ int sb[4];
    __shared__ __bf16 Ks[CH][72];        // [kj][d]  (d 0..63 + 8 pad)
    __shared__ __bf16 Vt[64][CH + 8];    // [d][kj]
    __shared__ __bf16 Ps[4][16][CH + 8]; // per-wave [qi][kj]

    if (threadIdx.x == 0) {
        int lo, hi;
        lo = 0; hi = TOTAL_Q;
        while (lo < hi) { int m = (lo + hi) >> 1; if (seg_q[m] <  s) lo = m + 1; else hi = m; }
        sb[0] = lo;
        hi = TOTAL_Q;
        while (lo < hi) { int m = (lo + hi) >> 1; if (seg_q[m] <= s) lo = m + 1; else hi = m; }
        sb[1] = lo;
        lo = 0; hi = TOTAL_KV;
        while (lo < hi) { int m = (lo + hi) >> 1; if (seg_kv[m] <  s) lo = m + 1; else hi = m; }
        sb[2] = lo;
        hi = TOTAL_KV;
        while (lo < hi) { int m = (lo + hi) >> 1; if (seg_kv[m] <= s) lo = m + 1; else hi = m; }
        sb[3] = lo;
    }
    __syncthreads();
    const int qbeg = sb[0], qend = sb[1], kbeg = sb[2], kend = sb[3];

    const int tid  = threadIdx.x;
    const int wave = tid >> 6, lane = tid & 63;
    const int quad = lane >> 4, l16 = lane & 15;

    for (int qt = qbeg; qt < qend; qt += 64) {
        // Q fragments straight from global (rows clamped; stores guarded later)
        const int qrow = qt + wave * 16 + l16;
        const int qrc  = min(qrow, qend - 1);
        bf16x8 qf[2];
        qf[0] = *(const bf16x8*)(qg + (size_t)qrc * DQK + h * 64 + quad * 8);
        qf[1] = *(const bf16x8*)(qg + (size_t)qrc * DQK + h * 64 + 32 + quad * 8);

        float m[4]  = { -1e30f, -1e30f, -1e30f, -1e30f };
        float l[4]  = { 0.f, 0.f, 0.f, 0.f };
        f32x4 acc[4] = {};

        for (int c0 = kbeg; c0 < kend; c0 += CH) {
            const int cl = min(CH, kend - c0);
            __syncthreads();   // prev chunk's LDS fully consumed

            // ---- stage K chunk: natural [kj][d], OOB rows zeroed
            #pragma unroll
            for (int it = 0; it < 2; ++it) {
                int e = (it * 256 + tid) * 8;
                int r = e >> 6, d = e & 63;
                bf16x8 z = {};
                if (r < cl)
                    z = *(const bf16x8*)(kg + (size_t)(c0 + r) * DQK + h * 64 + d);
                *(bf16x8*)&Ks[r][d] = z;
            }
            // ---- stage V chunk transposed: Vt[d][kj], OOB rows zeroed
            #pragma unroll
            for (int it = 0; it < 4; ++it) {
                int e = (it * 256 + tid) * 4;
                int r = e >> 6, d = e & 63;
                __bf16 t0 = 0, t1 = 0, t2 = 0, t3 = 0;
                if (r < cl) {
                    bf16x8 vv;
                    uint2 uu = *(const uint2*)(vg + (size_t)(c0 + r) * DV + h * 64 + d);
                    *(uint2*)&vv = uu;
                    t0 = vv[0]; t1 = vv[1]; t2 = vv[2]; t3 = vv[3];
                }
                Vt[d + 0][r] = t0; Vt[d + 1][r] = t1;
                Vt[d + 2][r] = t2; Vt[d + 3][r] = t3;
            }
            __syncthreads();

            // ---- S = q @ k^T : 4 col-tiles of 16, K-loop 2 (d=64)
            f32x4 sc[4];
            #pragma unroll
            for (int t = 0; t < 4; ++t) {
                bf16x8 b0 = *(const bf16x8*)&Ks[t * 16 + l16][quad * 8];
                bf16x8 b1 = *(const bf16x8*)&Ks[t * 16 + l16][32 + quad * 8];
                f32x4 z = {};
                z = __builtin_amdgcn_mfma_f32_16x16x32_bf16(qf[0], b0, z, 0, 0, 0);
                z = __builtin_amdgcn_mfma_f32_16x16x32_bf16(qf[1], b1, z, 0, 0, 0);
                sc[t] = z;
            }

            // ---- mask + scale
            float sv[4][4];
            #pragma unroll
            for (int t = 0; t < 4; ++t) {
                const bool ok = (c0 + t * 16 + l16) < kend;
                #pragma unroll
                for (int r = 0; r < 4; ++r)
                    sv[t][r] = ok ? sc[t][r] * SCALER : -1e30f;
            }

            // ---- online softmax per row (row = quad*4+r; reduce over l16)
            #pragma unroll
            for (int r = 0; r < 4; ++r) {
                float mx = fmaxf(fmaxf(sv[0][r], sv[1][r]), fmaxf(sv[2][r], sv[3][r]));
                mx = fmaxf(mx, __shfl_xor(mx, 1));
                mx = fmaxf(mx, __shfl_xor(mx, 2));
                mx = fmaxf(mx, __shfl_xor(mx, 4));
                mx = fmaxf(mx, __shfl_xor(mx, 8));
                const float mn = fmaxf(m[r], mx);
                const float alpha = __expf(m[r] - mn);
                m[r] = mn;
                float rs = 0.f;
                #pragma unroll
                for (int t = 0; t < 4; ++t) {
                    const float p = __expf(sv[t][r] - mn);
                    sv[t][r] = p;
                    rs += p;
                }
                rs += __shfl_xor(rs, 1);
                rs += __shfl_xor(rs, 2);
                rs += __shfl_xor(rs, 4);
                rs += __shfl_xor(rs, 8);
                l[r] = l[r] * alpha + rs;
                #pragma unroll
                for (int dt = 0; dt < 4; ++dt) acc[dt][r] *= alpha;
            }

            // ---- P -> LDS (bf16, per-wave slice, full 16x64 written)
            #pragma unroll
            for (int t = 0; t < 4; ++t)
                #pragma unroll
                for (int r = 0; r < 4; ++r)
                    Ps[wave][quad * 4 + r][t * 16 + l16] = (__bf16)sv[t][r];
            __syncthreads();   // visibility of Ps (and keeps waves together)

            // ---- O += P @ V
            #pragma unroll
            for (int ks = 0; ks < 2; ++ks) {
                bf16x8 pa = *(const bf16x8*)&Ps[wave][l16][ks * 32 + quad * 8];
                #pragma unroll
                for (int dt = 0; dt < 4; ++dt) {
                    bf16x8 vbf = *(const bf16x8*)&Vt[dt * 16 + l16][ks * 32 + quad * 8];
                    acc[dt] = __builtin_amdgcn_mfma_f32_16x16x32_bf16(pa, vbf, acc[dt], 0, 0, 0);
                }
            }
        }

        // ---- epilogue: normalize + store (C layout: col=l16 -> d, row=quad*4+r)
        float inv[4];
        #pragma unroll
        for (int r = 0; r < 4; ++r) inv[r] = 1.f / l[r];
        #pragma unroll
        for (int dt = 0; dt < 4; ++dt) {
            #pragma unroll
            for (int r = 0; r < 4; ++r) {
                const int row = qt + wave * 16 + quad * 4 + r;
                if (row < qend)
                    wv[(size_t)row * DV + h * 64 + dt * 16 + l16] =
                        __float2bfloat16(acc[dt][r] * inv[r]);
            }
        }
    }
}

// ---------------------------------------------------------------------------
extern "C" void kernel_launch(void* const* d_in, const int* in_sizes, int n_in,
                              void* d_out, int out_size, void* d_ws, size_t ws_size,
                              hipStream_t stream)
{
    const float* A     = (const float*)d_in[0];
    const float* B0    = (const float*)d_in[1];
    const int*   seg_q = (const int*)  d_in[2];
    const int*   seg_kv= (const int*)  d_in[3];
    const float* Wq    = (const float*)d_in[4];
    const float* bq    = (const float*)d_in[5];
    const float* Wk    = (const float*)d_in[6];
    const float* bk    = (const float*)d_in[7];
    const float* Wv    = (const float*)d_in[8];
    const float* bv    = (const float*)d_in[9];
    const float* Wf    = (const float*)d_in[10];
    const float* bf    = (const float*)d_in[11];
    float* out = (float*)d_out;

    // Workspace layout (bf16 elements), total 29.6 MB
    __hip_bfloat16* B0bf = (__hip_bfloat16*)d_ws;                 // 2048*1056
    __hip_bfloat16* Wqt  = B0bf + (size_t)TOTAL_KV * KVIN_P;      // 1024*1024
    __hip_bfloat16* Wkt  = Wqt  + (size_t)QIN * DQK;              // 1024*1056
    __hip_bfloat16* Wvt  = Wkt  + (size_t)DQK * KVIN_P;           // 1024*1056
    __hip_bfloat16* Wft  = Wvt  + (size_t)DV * KVIN_P;            // 1024*1024
    __hip_bfloat16* Abf  = Wft  + (size_t)DV * QIN;               // 2048*1024
    __hip_bfloat16* qb   = Abf  + (size_t)TOTAL_Q * QIN;          // 2048*1024
    __hip_bfloat16* kb   = qb   + (size_t)TOTAL_Q * DQK;          // 2048*1024
    __hip_bfloat16* vb   = kb   + (size_t)TOTAL_KV * DQK;         // 2048*1024
    __hip_bfloat16* wvb  = Abf;  // alias: Abf dead after q-projection

    const dim3 b256(256);

    // Casts / transposes
    cast_bf16_k<<<dim3((TOTAL_Q * QIN / 4 + 255) / 256), b256, 0, stream>>>(A, Abf, TOTAL_Q * QIN);
    cast_pad_k<<<dim3((TOTAL_KV * KVIN_P + 255) / 256), b256, 0, stream>>>(B0, B0bf);
    transpose_cast_k<<<dim3(DQK / 32, QIN / 32), dim3(32, 8), 0, stream>>>(Wq, Wqt, QIN,  DQK);
    transpose_cast_k<<<dim3(KVIN_P / 32, DQK / 32), dim3(32, 8), 0, stream>>>(Wk, Wkt, KVIN, KVIN_P);
    transpose_cast_k<<<dim3(KVIN_P / 32, DV  / 32), dim3(32, 8), 0, stream>>>(Wv, Wvt, KVIN, KVIN_P);
    transpose_cast_k<<<dim3(DV / 32, QIN / 32), dim3(32, 8), 0, stream>>>(Wf, Wft, DV, QIN);

    // Projections (bf16 out)
    const dim3 gg(DQK / 64, TOTAL_Q / 64);   // (16, 32) = 512 blocks
    gemm_mfma<1><<<gg, b256, 0, stream>>>(Abf,  Wqt, bq, qb, TOTAL_Q,  DQK, QIN);
    gemm_mfma<1><<<gg, b256, 0, stream>>>(B0bf, Wkt, bk, kb, TOTAL_KV, DQK, KVIN_P);
    gemm_mfma<1><<<gg, b256, 0, stream>>>(B0bf, Wvt, bv, vb, TOTAL_KV, DV,  KVIN_P);

    // Attention: block per (segment, head)
    attn_mfma<<<dim3(32 * 16), b256, 0, stream>>>(qb, kb, vb, seg_q, seg_kv, wvb);

    // Output projection (fp32 out)
    gemm_mfma<0><<<gg, b256, 0, stream>>>(wvb, Wft, bf, out, TOTAL_Q, QIN, DV);
}

// Round 4
// 185.036 us; speedup vs baseline: 4.1224x; 1.0972x over previous
//
#include <hip/hip_runtime.h>
#include <hip/hip_bf16.h>
#include <math.h>

#define TOTAL_Q   2048
#define TOTAL_KV  2048
#define QIN       1024
#define KVIN      1033
#define KVIN_P    1056      // KVIN padded to multiple of 32 (zero-filled)
#define DQK       1024
#define DV        1024
#define KVSTR     2048      // fused [k|v] row stride
#define SCALER    0.125f    // 1/sqrt(64)

typedef __bf16 bf16x8 __attribute__((ext_vector_type(8)));
typedef float  f32x4  __attribute__((ext_vector_type(4)));

// async global->LDS, 16 B per lane; LDS dest = wave-uniform base + lane*16
__device__ __forceinline__ void glds16(const __hip_bfloat16* g, __bf16* l)
{
    __builtin_amdgcn_global_load_lds(
        (const __attribute__((address_space(1))) void*)g,
        (__attribute__((address_space(3))) void*)l,
        16, 0, 0);
}

// ---------------------------------------------------------------------------
// fp32 -> bf16 cast (n multiple of 4)
// ---------------------------------------------------------------------------
__global__ __launch_bounds__(256)
void cast_bf16_k(const float* __restrict__ in, __hip_bfloat16* __restrict__ out, int n)
{
    int i = (blockIdx.x * 256 + threadIdx.x) * 4;
    if (i >= n) return;
    float4 f = *(const float4*)(in + i);
    __hip_bfloat16 o[4] = { __float2bfloat16(f.x), __float2bfloat16(f.y),
                            __float2bfloat16(f.z), __float2bfloat16(f.w) };
    *(uint2*)(out + i) = *(const uint2*)o;
}

// fp32 [2048][1033] -> bf16 [2048][1056], cols >= 1033 zero-filled
__global__ __launch_bounds__(256)
void cast_pad_k(const float* __restrict__ in, __hip_bfloat16* __restrict__ out)
{
    int idx = blockIdx.x * 256 + threadIdx.x;
    if (idx >= TOTAL_KV * KVIN_P) return;
    int r = idx / KVIN_P, c = idx - r * KVIN_P;
    float v = (c < KVIN) ? in[(size_t)r * KVIN + c] : 0.f;
    out[idx] = __float2bfloat16(v);
}

// two W[K][1024] fp32 -> Wt[1024][Kp] bf16 (transposed, k >= K zero-filled)
__global__ __launch_bounds__(256)
void transpose_cast2_k(const float* __restrict__ W0, const float* __restrict__ W1,
                       __hip_bfloat16* __restrict__ D0, __hip_bfloat16* __restrict__ D1,
                       int K, int Kp)
{
    const float* W = blockIdx.z ? W1 : W0;
    __hip_bfloat16* Wt = blockIdx.z ? D1 : D0;
    __shared__ float tile[32][33];
    const int k0 = blockIdx.x * 32, n0 = blockIdx.y * 32;
    #pragma unroll
    for (int i = 0; i < 4; ++i) {
        int k = k0 + threadIdx.y + i * 8;
        tile[threadIdx.y + i * 8][threadIdx.x] =
            (k < K) ? W[(size_t)k * 1024 + n0 + threadIdx.x] : 0.f;
    }
    __syncthreads();
    #pragma unroll
    for (int i = 0; i < 4; ++i) {
        int n = n0 + threadIdx.y + i * 8;
        Wt[(size_t)n * Kp + k0 + threadIdx.x] =
            __float2bfloat16(tile[threadIdx.x][threadIdx.y + i * 8]);
    }
}

// ---------------------------------------------------------------------------
// bf16 MFMA GEMM, m97-style staging:  C[M,N] = A[M,K] @ Bt[N,K]^T + bias
// BM=128, BN=64, BK=32. 256 threads = 4 waves; wave tile 64x32 (4x2 MFMAs of
// 16x16x32). Staging via global_load_lds width=16: A-tile = 8 chunks of 1 KB
// (16 rows ea), B-tile = 4 chunks; LDS unpadded [rows][32] so lane order is
// contiguous (required by the wave-uniform-base + lane*16 semantics).
// Requires: M%128==0, N%64==0, K%32==0, A/Bt 16B-aligned, row strides %8==0.
// bias split: col < nsplit -> biasA[col], else biasB[col-nsplit].
// ---------------------------------------------------------------------------
template<int OUT_BF16>
__global__ __launch_bounds__(256)
void gemm_glds(const __hip_bfloat16* __restrict__ A,
               const __hip_bfloat16* __restrict__ Bt,
               const float* __restrict__ biasA, const float* __restrict__ biasB,
               int nsplit,
               void* __restrict__ Cv,
               int M, int N, int K)
{
    __shared__ __bf16 As[128 * 32];   // 8 KB
    __shared__ __bf16 Bs[64 * 32];    // 4 KB

    const int tid  = threadIdx.x;
    const int wave = tid >> 6, lane = tid & 63;
    const int quad = lane >> 4, l16 = lane & 15;
    const int wm = (wave >> 1) * 64;        // wave row offset in tile
    const int wn = (wave & 1) * 32;         // wave col offset in tile
    const int row0 = blockIdx.y * 128, col0 = blockIdx.x * 64;

    // staging lane geometry: chunk = 16 rows; lane covers row cr, 8-elem col cc
    const int cr = lane >> 2;
    const int cc = (lane & 3) * 8;

    // per-lane global base pointers for this wave's chunks
    const __hip_bfloat16* ga0 = A  + (size_t)(row0 + (wave * 2 + 0) * 16 + cr) * K + cc;
    const __hip_bfloat16* ga1 = A  + (size_t)(row0 + (wave * 2 + 1) * 16 + cr) * K + cc;
    const __hip_bfloat16* gb0 = Bt + (size_t)(col0 + wave * 16 + cr) * K + cc;

    f32x4 acc[4][2] = {};

    for (int k0 = 0; k0 < K; k0 += 32) {
        glds16(ga0 + k0, &As[(wave * 2 + 0) * 512]);
        glds16(ga1 + k0, &As[(wave * 2 + 1) * 512]);
        glds16(gb0 + k0, &Bs[wave * 512]);
        __syncthreads();   // compiler drains vmcnt before barrier

        bf16x8 af[4], bfr[2];
        #pragma unroll
        for (int mi = 0; mi < 4; ++mi)
            af[mi] = *(const bf16x8*)&As[(wm + mi * 16 + l16) * 32 + quad * 8];
        #pragma unroll
        for (int ni = 0; ni < 2; ++ni)
            bfr[ni] = *(const bf16x8*)&Bs[(wn + ni * 16 + l16) * 32 + quad * 8];

        #pragma unroll
        for (int mi = 0; mi < 4; ++mi)
            #pragma unroll
            for (int ni = 0; ni < 2; ++ni)
                acc[mi][ni] = __builtin_amdgcn_mfma_f32_16x16x32_bf16(
                    af[mi], bfr[ni], acc[mi][ni], 0, 0, 0);
        __syncthreads();   // LDS consumed before next stage
    }

    #pragma unroll
    for (int mi = 0; mi < 4; ++mi) {
        #pragma unroll
        for (int ni = 0; ni < 2; ++ni) {
            const int col = col0 + wn + ni * 16 + l16;
            const float b = (col < nsplit) ? biasA[col] : biasB[col - nsplit];
            #pragma unroll
            for (int r = 0; r < 4; ++r) {
                const int row = row0 + wm + mi * 16 + quad * 4 + r;
                const float val = acc[mi][ni][r] + b;
                if (OUT_BF16)
                    ((__hip_bfloat16*)Cv)[(size_t)row * N + col] = __float2bfloat16(val);
                else
                    ((float*)Cv)[(size_t)row * N + col] = val;
            }
        }
    }
}

// ---------------------------------------------------------------------------
// MFMA flash attention over ragged segments (unchanged math from R2; k/v now
// read from the fused [k|v] buffer with row stride KVSTR).
// Block = (segment s, head h). 256 threads = 4 waves; q-tiles of 64 rows,
// kv chunks of CH=64 through LDS.
// ---------------------------------------------------------------------------
#define CH 64

__global__ __launch_bounds__(256)
void attn_mfma(const __hip_bfloat16* __restrict__ qg,
               const __hip_bfloat16* __restrict__ kg,   // kvb
               const __hip_bfloat16* __restrict__ vg,   // kvb + 1024
               const int* __restrict__ seg_q, const int* __restrict__ seg_kv,
               __hip_bfloat16* __restrict__ wv)
{
    const int h = blockIdx.x & 15;
    const int s = blockIdx.x >> 4;

    __shared__ int sb[4];
    __shared__ __bf16 Ks[CH][72];
    __shared__ __bf16 Vt[64][CH + 8];
    __shared__ __bf16 Ps[4][16][CH + 8];

    if (threadIdx.x == 0) {
        int lo, hi;
        lo = 0; hi = TOTAL_Q;
        while (lo < hi) { int m = (lo + hi) >> 1; if (seg_q[m] <  s) lo = m + 1; else hi = m; }
        sb[0] = lo;
        hi = TOTAL_Q;
        while (lo < hi) { int m = (lo + hi) >> 1; if (seg_q[m] <= s) lo = m + 1; else hi = m; }
        sb[1] = lo;
        lo = 0; hi = TOTAL_KV;
        while (lo < hi) { int m = (lo + hi) >> 1; if (seg_kv[m] <  s) lo = m + 1; else hi = m; }
        sb[2] = lo;
        hi = TOTAL_KV;
        while (lo < hi) { int m = (lo + hi) >> 1; if (seg_kv[m] <= s) lo = m + 1; else hi = m; }
        sb[3] = lo;
    }
    __syncthreads();
    const int qbeg = sb[0], qend = sb[1], kbeg = sb[2], kend = sb[3];

    const int tid  = threadIdx.x;
    const int wave = tid >> 6, lane = tid & 63;
    const int quad = lane >> 4, l16 = lane & 15;

    for (int qt = qbeg; qt < qend; qt += 64) {
        const int qrow = qt + wave * 16 + l16;
        const int qrc  = min(qrow, qend - 1);
        bf16x8 qf[2];
        qf[0] = *(const bf16x8*)(qg + (size_t)qrc * DQK + h * 64 + quad * 8);
        qf[1] = *(const bf16x8*)(qg + (size_t)qrc * DQK + h * 64 + 32 + quad * 8);

        float m[4]  = { -1e30f, -1e30f, -1e30f, -1e30f };
        float l[4]  = { 0.f, 0.f, 0.f, 0.f };
        f32x4 acc[4] = {};

        for (int c0 = kbeg; c0 < kend; c0 += CH) {
            const int cl = min(CH, kend - c0);
            __syncthreads();

            #pragma unroll
            for (int it = 0; it < 2; ++it) {
                int e = (it * 256 + tid) * 8;
                int r = e >> 6, d = e & 63;
                bf16x8 z = {};
                if (r < cl)
                    z = *(const bf16x8*)(kg + (size_t)(c0 + r) * KVSTR + h * 64 + d);
                *(bf16x8*)&Ks[r][d] = z;
            }
            #pragma unroll
            for (int it = 0; it < 4; ++it) {
                int e = (it * 256 + tid) * 4;
                int r = e >> 6, d = e & 63;
                __bf16 t0 = 0, t1 = 0, t2 = 0, t3 = 0;
                if (r < cl) {
                    bf16x8 vv;
                    uint2 uu = *(const uint2*)(vg + (size_t)(c0 + r) * KVSTR + h * 64 + d);
                    *(uint2*)&vv = uu;
                    t0 = vv[0]; t1 = vv[1]; t2 = vv[2]; t3 = vv[3];
                }
                Vt[d + 0][r] = t0; Vt[d + 1][r] = t1;
                Vt[d + 2][r] = t2; Vt[d + 3][r] = t3;
            }
            __syncthreads();

            f32x4 sc[4];
            #pragma unroll
            for (int t = 0; t < 4; ++t) {
                bf16x8 b0 = *(const bf16x8*)&Ks[t * 16 + l16][quad * 8];
                bf16x8 b1 = *(const bf16x8*)&Ks[t * 16 + l16][32 + quad * 8];
                f32x4 z = {};
                z = __builtin_amdgcn_mfma_f32_16x16x32_bf16(qf[0], b0, z, 0, 0, 0);
                z = __builtin_amdgcn_mfma_f32_16x16x32_bf16(qf[1], b1, z, 0, 0, 0);
                sc[t] = z;
            }

            float sv[4][4];
            #pragma unroll
            for (int t = 0; t < 4; ++t) {
                const bool ok = (c0 + t * 16 + l16) < kend;
                #pragma unroll
                for (int r = 0; r < 4; ++r)
                    sv[t][r] = ok ? sc[t][r] * SCALER : -1e30f;
            }

            #pragma unroll
            for (int r = 0; r < 4; ++r) {
                float mx = fmaxf(fmaxf(sv[0][r], sv[1][r]), fmaxf(sv[2][r], sv[3][r]));
                mx = fmaxf(mx, __shfl_xor(mx, 1));
                mx = fmaxf(mx, __shfl_xor(mx, 2));
                mx = fmaxf(mx, __shfl_xor(mx, 4));
                mx = fmaxf(mx, __shfl_xor(mx, 8));
                const float mn = fmaxf(m[r], mx);
                const float alpha = __expf(m[r] - mn);
                m[r] = mn;
                float rs = 0.f;
                #pragma unroll
                for (int t = 0; t < 4; ++t) {
                    const float p = __expf(sv[t][r] - mn);
                    sv[t][r] = p;
                    rs += p;
                }
                rs += __shfl_xor(rs, 1);
                rs += __shfl_xor(rs, 2);
                rs += __shfl_xor(rs, 4);
                rs += __shfl_xor(rs, 8);
                l[r] = l[r] * alpha + rs;
                #pragma unroll
                for (int dt = 0; dt < 4; ++dt) acc[dt][r] *= alpha;
            }

            #pragma unroll
            for (int t = 0; t < 4; ++t)
                #pragma unroll
                for (int r = 0; r < 4; ++r)
                    Ps[wave][quad * 4 + r][t * 16 + l16] = (__bf16)sv[t][r];
            __syncthreads();

            #pragma unroll
            for (int ks = 0; ks < 2; ++ks) {
                bf16x8 pa = *(const bf16x8*)&Ps[wave][l16][ks * 32 + quad * 8];
                #pragma unroll
                for (int dt = 0; dt < 4; ++dt) {
                    bf16x8 vbf = *(const bf16x8*)&Vt[dt * 16 + l16][ks * 32 + quad * 8];
                    acc[dt] = __builtin_amdgcn_mfma_f32_16x16x32_bf16(pa, vbf, acc[dt], 0, 0, 0);
                }
            }
        }

        float inv[4];
        #pragma unroll
        for (int r = 0; r < 4; ++r) inv[r] = 1.f / l[r];
        #pragma unroll
        for (int dt = 0; dt < 4; ++dt) {
            #pragma unroll
            for (int r = 0; r < 4; ++r) {
                const int row = qt + wave * 16 + quad * 4 + r;
                if (row < qend)
                    wv[(size_t)row * DV + h * 64 + dt * 16 + l16] =
                        __float2bfloat16(acc[dt][r] * inv[r]);
            }
        }
    }
}

// ---------------------------------------------------------------------------
extern "C" void kernel_launch(void* const* d_in, const int* in_sizes, int n_in,
                              void* d_out, int out_size, void* d_ws, size_t ws_size,
                              hipStream_t stream)
{
    const float* A     = (const float*)d_in[0];
    const float* B0    = (const float*)d_in[1];
    const int*   seg_q = (const int*)  d_in[2];
    const int*   seg_kv= (const int*)  d_in[3];
    const float* Wq    = (const float*)d_in[4];
    const float* bq    = (const float*)d_in[5];
    const float* Wk    = (const float*)d_in[6];
    const float* bk    = (const float*)d_in[7];
    const float* Wv    = (const float*)d_in[8];
    const float* bv    = (const float*)d_in[9];
    const float* Wf    = (const float*)d_in[10];
    const float* bf    = (const float*)d_in[11];
    float* out = (float*)d_out;

    // Workspace (bf16 elems), 29.6 MB total; all offsets 16B-aligned
    __hip_bfloat16* B0bf = (__hip_bfloat16*)d_ws;                 // 2048*1056
    __hip_bfloat16* Wqt  = B0bf + (size_t)TOTAL_KV * KVIN_P;      // 1024*1024
    __hip_bfloat16* Wkt  = Wqt  + (size_t)QIN * DQK;              // 1024*1056  \ fused
    __hip_bfloat16* Wvt  = Wkt  + (size_t)DQK * KVIN_P;           // 1024*1056  / [2048][1056]
    __hip_bfloat16* Wft  = Wvt  + (size_t)DV * KVIN_P;            // 1024*1024
    __hip_bfloat16* Abf  = Wft  + (size_t)DV * QIN;               // 2048*1024
    __hip_bfloat16* qb   = Abf  + (size_t)TOTAL_Q * QIN;          // 2048*1024
    __hip_bfloat16* kvb  = qb   + (size_t)TOTAL_Q * DQK;          // 2048*2048 fused [k|v]
    __hip_bfloat16* wvb  = Abf;  // alias: Abf dead after q-projection

    const dim3 b256(256);

    cast_bf16_k<<<dim3((TOTAL_Q * QIN / 4 + 255) / 256), b256, 0, stream>>>(A, Abf, TOTAL_Q * QIN);
    cast_pad_k<<<dim3((TOTAL_KV * KVIN_P + 255) / 256), b256, 0, stream>>>(B0, B0bf);
    transpose_cast2_k<<<dim3(DQK / 32, 1024 / 32, 2), dim3(32, 8), 0, stream>>>(
        Wq, Wf, Wqt, Wft, QIN, DQK);
    transpose_cast2_k<<<dim3(KVIN_P / 32, 1024 / 32, 2), dim3(32, 8), 0, stream>>>(
        Wk, Wv, Wkt, Wvt, KVIN, KVIN_P);

    // Q projection: 2048x1024x1024 -> 256 blocks
    gemm_glds<1><<<dim3(DQK / 64, TOTAL_Q / 128), b256, 0, stream>>>(
        Abf, Wqt, bq, bq, DQK, qb, TOTAL_Q, DQK, QIN);
    // fused K|V projection: 2048x2048x1056 -> 512 blocks
    gemm_glds<1><<<dim3(KVSTR / 64, TOTAL_KV / 128), b256, 0, stream>>>(
        B0bf, Wkt, bk, bv, 1024, kvb, TOTAL_KV, KVSTR, KVIN_P);

    attn_mfma<<<dim3(32 * 16), b256, 0, stream>>>(qb, kvb, kvb + 1024, seg_q, seg_kv, wvb);

    // output projection (fp32 out): 2048x1024x1024 -> 256 blocks
    gemm_glds<0><<<dim3(QIN / 64, TOTAL_Q / 128), b256, 0, stream>>>(
        wvb, Wft, bf, bf, QIN, out, TOTAL_Q, QIN, DV);
}

// Round 5
// 173.537 us; speedup vs baseline: 4.3955x; 1.0663x over previous
//
#include <hip/hip_runtime.h>
#include <hip/hip_bf16.h>
#include <math.h>

#define TOTAL_Q   2048
#define TOTAL_KV  2048
#define QIN       1024
#define KVIN      1033
#define KVIN_P    1056      // KVIN padded to multiple of 32 (zero-filled)
#define DQK       1024
#define DV        1024
#define KVSTR     2048      // fused [k|v] row stride
#define SCALER    0.125f    // 1/sqrt(64)

typedef __bf16 bf16x8 __attribute__((ext_vector_type(8)));
typedef float  f32x4  __attribute__((ext_vector_type(4)));

// async global->LDS, 16 B per lane; LDS dest = wave-uniform base + lane*16
__device__ __forceinline__ void glds16(const __hip_bfloat16* g, __bf16* l)
{
    __builtin_amdgcn_global_load_lds(
        (const __attribute__((address_space(1))) void*)g,
        (__attribute__((address_space(3))) void*)l,
        16, 0, 0);
}

// ---------------------------------------------------------------------------
// Fused prep: one launch, flat grid, block ranges:
//   [0,2048)      : cast A fp32->bf16            (2048x1024, 4 elem/thread)
//   [2048,4160)   : cast+pad B0 -> [2048][1056]  (4 elem/thread, row-aligned)
//   [4160,6208)   : transpose Wq|Wf  [1024][1024] -> [1024][1024]
//   [6208,8320)   : transpose Wk|Wv  [1033][1024] -> [1024][1056]
// ---------------------------------------------------------------------------
__global__ __launch_bounds__(256)
void prep_k(const float* __restrict__ A,  const float* __restrict__ B0,
            const float* __restrict__ Wq, const float* __restrict__ Wk,
            const float* __restrict__ Wv, const float* __restrict__ Wf,
            __hip_bfloat16* __restrict__ Abf, __hip_bfloat16* __restrict__ B0bf,
            __hip_bfloat16* __restrict__ Wqt, __hip_bfloat16* __restrict__ Wkt,
            __hip_bfloat16* __restrict__ Wvt, __hip_bfloat16* __restrict__ Wft)
{
    const int b   = blockIdx.x;
    const int tid = threadIdx.x;

    if (b < 2048) {                       // ---- cast A
        int i = (b * 256 + tid) * 4;
        float4 f = *(const float4*)(A + i);
        __hip_bfloat16 o[4] = { __float2bfloat16(f.x), __float2bfloat16(f.y),
                                __float2bfloat16(f.z), __float2bfloat16(f.w) };
        *(uint2*)(Abf + i) = *(const uint2*)o;
        return;
    }
    if (b < 4160) {                       // ---- cast+pad B0
        int idx = ((b - 2048) * 256 + tid) * 4;       // padded-elem index
        int r = idx / KVIN_P, c = idx - r * KVIN_P;   // 4-groups never cross rows
        __hip_bfloat16 o[4];
        #pragma unroll
        for (int j = 0; j < 4; ++j)
            o[j] = __float2bfloat16((c + j < KVIN) ? B0[(size_t)r * KVIN + c + j] : 0.f);
        *(uint2*)(B0bf + idx) = *(const uint2*)o;
        return;
    }

    // ---- transposes: W[K][1024] -> Wt[1024][Kp], zero-fill k >= K
    const float* W; __hip_bfloat16* Wt; int K, Kp, k0, n0;
    if (b < 6208) {
        int z = b - 4160;                 // 2 x 1024 blocks, 32x32 tiles
        W  = (z >= 1024) ? Wf : Wq;
        Wt = (z >= 1024) ? Wft : Wqt;
        K = 1024; Kp = 1024;
        int rem = z & 1023;
        k0 = (rem & 31) * 32; n0 = (rem >> 5) * 32;
    } else {
        int z = b - 6208;                 // 2 x 1056 blocks (33 k-tiles x 32 n-tiles)
        W  = (z >= 1056) ? Wv : Wk;
        Wt = (z >= 1056) ? Wvt : Wkt;
        K = KVIN; Kp = KVIN_P;
        int rem = (z >= 1056) ? z - 1056 : z;
        k0 = (rem % 33) * 32; n0 = (rem / 33) * 32;
    }
    const int tx = tid & 31, ty = tid >> 5;   // (32,8)
    __shared__ float tile[32][33];
    #pragma unroll
    for (int i = 0; i < 4; ++i) {
        int k = k0 + ty + i * 8;
        tile[ty + i * 8][tx] = (k < K) ? W[(size_t)k * 1024 + n0 + tx] : 0.f;
    }
    __syncthreads();
    #pragma unroll
    for (int i = 0; i < 4; ++i) {
        int n = n0 + ty + i * 8;
        Wt[(size_t)n * Kp + k0 + tx] = __float2bfloat16(tile[tx][ty + i * 8]);
    }
}

// ---------------------------------------------------------------------------
// Grouped Q + fused-KV projection, m97 geometry.
// One grid: blocks [0,128) = Q-proj (2048x1024 @ K=1024),
//           blocks [128,384) = KV-proj (2048x2048 @ K=1056, bias split at 1024).
// BM=BN=128, BK=32; 256 threads = 4 waves, each wave 64x64 (4x4 MFMAs of
// 16x16x32; 16 MFMA : 8 ds_read_b128 per K-step). Staging: 16 glds16 chunks
// (1 KB each: 16 rows x 32 elems), 4 per wave. LDS 16 KB, unpadded (lane-order
// contiguous as global_load_lds requires).
// ---------------------------------------------------------------------------
__global__ __launch_bounds__(256)
void gemm_qkv(const __hip_bfloat16* __restrict__ Abf,
              const __hip_bfloat16* __restrict__ Wqt,
              const float* __restrict__ bq,
              __hip_bfloat16* __restrict__ qb,
              const __hip_bfloat16* __restrict__ B0bf,
              const __hip_bfloat16* __restrict__ Wkvt,
              const float* __restrict__ bk, const float* __restrict__ bv,
              __hip_bfloat16* __restrict__ kvb)
{
    __shared__ __bf16 As[128 * 32];   // 8 KB
    __shared__ __bf16 Bs[128 * 32];   // 8 KB

    int b = blockIdx.x;
    const __hip_bfloat16 *Ag, *Btg; const float *bias0, *bias1;
    __hip_bfloat16* C; int N, K, bx, by;
    if (b < 128) {        // Q: grid 8 cols x 16 rows
        Ag = Abf; Btg = Wqt; bias0 = bq; bias1 = bq; C = qb;
        N = 1024; K = 1024; bx = b & 7; by = b >> 3;
    } else {              // KV: grid 16 cols x 16 rows
        b -= 128;
        Ag = B0bf; Btg = Wkvt; bias0 = bk; bias1 = bv; C = kvb;
        N = 2048; K = KVIN_P; bx = b & 15; by = b >> 4;
    }
    const int row0 = by * 128, col0 = bx * 128;

    const int tid  = threadIdx.x;
    const int wave = tid >> 6, lane = tid & 63;
    const int quad = lane >> 4, l16 = lane & 15;
    const int wm = (wave >> 1) * 64, wn = (wave & 1) * 64;

    // staging: chunk = 16 rows x 32 elems; lane covers row cr, 8-col group cc
    const int cr = lane >> 2;
    const int cc = (lane & 3) * 8;

    // wave w stages chunks w*4 .. w*4+3 (0..7 -> A rows, 8..15 -> B rows)
    const __hip_bfloat16* gsrc[4];
    __bf16* ldst[4];
    #pragma unroll
    for (int i = 0; i < 4; ++i) {
        int c = wave * 4 + i;
        if (c < 8) {
            gsrc[i] = Ag  + (size_t)(row0 + c * 16 + cr) * K + cc;
            ldst[i] = &As[c * 512];
        } else {
            gsrc[i] = Btg + (size_t)(col0 + (c - 8) * 16 + cr) * K + cc;
            ldst[i] = &Bs[(c - 8) * 512];
        }
    }

    f32x4 acc[4][4] = {};

    for (int k0 = 0; k0 < K; k0 += 32) {
        #pragma unroll
        for (int i = 0; i < 4; ++i)
            glds16(gsrc[i] + k0, ldst[i]);
        __syncthreads();

        bf16x8 af[4], bfr[4];
        #pragma unroll
        for (int mi = 0; mi < 4; ++mi)
            af[mi] = *(const bf16x8*)&As[(wm + mi * 16 + l16) * 32 + quad * 8];
        #pragma unroll
        for (int ni = 0; ni < 4; ++ni)
            bfr[ni] = *(const bf16x8*)&Bs[(wn + ni * 16 + l16) * 32 + quad * 8];

        #pragma unroll
        for (int mi = 0; mi < 4; ++mi)
            #pragma unroll
            for (int ni = 0; ni < 4; ++ni)
                acc[mi][ni] = __builtin_amdgcn_mfma_f32_16x16x32_bf16(
                    af[mi], bfr[ni], acc[mi][ni], 0, 0, 0);
        __syncthreads();
    }

    #pragma unroll
    for (int mi = 0; mi < 4; ++mi) {
        #pragma unroll
        for (int ni = 0; ni < 4; ++ni) {
            const int col = col0 + wn + ni * 16 + l16;
            const float bia = (col < 1024) ? bias0[col] : bias1[col - 1024];
            #pragma unroll
            for (int r = 0; r < 4; ++r) {
                const int row = row0 + wm + mi * 16 + quad * 4 + r;
                C[(size_t)row * N + col] = __float2bfloat16(acc[mi][ni][r] + bia);
            }
        }
    }
}

// ---------------------------------------------------------------------------
// Output projection (R4 structure, proven): C = A @ Bt^T + bias, fp32 out.
// BM=128, BN=64, BK=32; 4 waves each 64x32.
// ---------------------------------------------------------------------------
__global__ __launch_bounds__(256)
void gemm_out(const __hip_bfloat16* __restrict__ A,
              const __hip_bfloat16* __restrict__ Bt,
              const float* __restrict__ bias,
              float* __restrict__ C,
              int M, int N, int K)
{
    __shared__ __bf16 As[128 * 32];
    __shared__ __bf16 Bs[64 * 32];

    const int tid  = threadIdx.x;
    const int wave = tid >> 6, lane = tid & 63;
    const int quad = lane >> 4, l16 = lane & 15;
    const int wm = (wave >> 1) * 64;
    const int wn = (wave & 1) * 32;
    const int row0 = blockIdx.y * 128, col0 = blockIdx.x * 64;

    const int cr = lane >> 2;
    const int cc = (lane & 3) * 8;

    const __hip_bfloat16* ga0 = A  + (size_t)(row0 + (wave * 2 + 0) * 16 + cr) * K + cc;
    const __hip_bfloat16* ga1 = A  + (size_t)(row0 + (wave * 2 + 1) * 16 + cr) * K + cc;
    const __hip_bfloat16* gb0 = Bt + (size_t)(col0 + wave * 16 + cr) * K + cc;

    f32x4 acc[4][2] = {};

    for (int k0 = 0; k0 < K; k0 += 32) {
        glds16(ga0 + k0, &As[(wave * 2 + 0) * 512]);
        glds16(ga1 + k0, &As[(wave * 2 + 1) * 512]);
        glds16(gb0 + k0, &Bs[wave * 512]);
        __syncthreads();

        bf16x8 af[4], bfr[2];
        #pragma unroll
        for (int mi = 0; mi < 4; ++mi)
            af[mi] = *(const bf16x8*)&As[(wm + mi * 16 + l16) * 32 + quad * 8];
        #pragma unroll
        for (int ni = 0; ni < 2; ++ni)
            bfr[ni] = *(const bf16x8*)&Bs[(wn + ni * 16 + l16) * 32 + quad * 8];

        #pragma unroll
        for (int mi = 0; mi < 4; ++mi)
            #pragma unroll
            for (int ni = 0; ni < 2; ++ni)
                acc[mi][ni] = __builtin_amdgcn_mfma_f32_16x16x32_bf16(
                    af[mi], bfr[ni], acc[mi][ni], 0, 0, 0);
        __syncthreads();
    }

    #pragma unroll
    for (int mi = 0; mi < 4; ++mi) {
        #pragma unroll
        for (int ni = 0; ni < 2; ++ni) {
            const int col = col0 + wn + ni * 16 + l16;
            const float b = bias[col];
            #pragma unroll
            for (int r = 0; r < 4; ++r) {
                const int row = row0 + wm + mi * 16 + quad * 4 + r;
                C[(size_t)row * N + col] = acc[mi][ni][r] + b;
            }
        }
    }
}

// ---------------------------------------------------------------------------
// MFMA flash attention over ragged segments (unchanged from R3/R4).
// ---------------------------------------------------------------------------
#define CH 64

__global__ __launch_bounds__(256)
void attn_mfma(const __hip_bfloat16* __restrict__ qg,
               const __hip_bfloat16* __restrict__ kg,   // kvb
               const __hip_bfloat16* __restrict__ vg,   // kvb + 1024
               const int* __restrict__ seg_q, const int* __restrict__ seg_kv,
               __hip_bfloat16* __restrict__ wv)
{
    const int h = blockIdx.x & 15;
    const int s = blockIdx.x >> 4;

    __shared__ int sb[4];
    __shared__ __bf16 Ks[CH][72];
    __shared__ __bf16 Vt[64][CH + 8];
    __shared__ __bf16 Ps[4][16][CH + 8];

    if (threadIdx.x == 0) {
        int lo, hi;
        lo = 0; hi = TOTAL_Q;
        while (lo < hi) { int m = (lo + hi) >> 1; if (seg_q[m] <  s) lo = m + 1; else hi = m; }
        sb[0] = lo;
        hi = TOTAL_Q;
        while (lo < hi) { int m = (lo + hi) >> 1; if (seg_q[m] <= s) lo = m + 1; else hi = m; }
        sb[1] = lo;
        lo = 0; hi = TOTAL_KV;
        while (lo < hi) { int m = (lo + hi) >> 1; if (seg_kv[m] <  s) lo = m + 1; else hi = m; }
        sb[2] = lo;
        hi = TOTAL_KV;
        while (lo < hi) { int m = (lo + hi) >> 1; if (seg_kv[m] <= s) lo = m + 1; else hi = m; }
        sb[3] = lo;
    }
    __syncthreads();
    const int qbeg = sb[0], qend = sb[1], kbeg = sb[2], kend = sb[3];

    const int tid  = threadIdx.x;
    const int wave = tid >> 6, lane = tid & 63;
    const int quad = lane >> 4, l16 = lane & 15;

    for (int qt = qbeg; qt < qend; qt += 64) {
        const int qrow = qt + wave * 16 + l16;
        const int qrc  = min(qrow, qend - 1);
        bf16x8 qf[2];
        qf[0] = *(const bf16x8*)(qg + (size_t)qrc * DQK + h * 64 + quad * 8);
        qf[1] = *(const bf16x8*)(qg + (size_t)qrc * DQK + h * 64 + 32 + quad * 8);

        float m[4]  = { -1e30f, -1e30f, -1e30f, -1e30f };
        float l[4]  = { 0.f, 0.f, 0.f, 0.f };
        f32x4 acc[4] = {};

        for (int c0 = kbeg; c0 < kend; c0 += CH) {
            const int cl = min(CH, kend - c0);
            __syncthreads();

            #pragma unroll
            for (int it = 0; it < 2; ++it) {
                int e = (it * 256 + tid) * 8;
                int r = e >> 6, d = e & 63;
                bf16x8 z = {};
                if (r < cl)
                    z = *(const bf16x8*)(kg + (size_t)(c0 + r) * KVSTR + h * 64 + d);
                *(bf16x8*)&Ks[r][d] = z;
            }
            #pragma unroll
            for (int it = 0; it < 4; ++it) {
                int e = (it * 256 + tid) * 4;
                int r = e >> 6, d = e & 63;
                __bf16 t0 = 0, t1 = 0, t2 = 0, t3 = 0;
                if (r < cl) {
                    bf16x8 vv;
                    uint2 uu = *(const uint2*)(vg + (size_t)(c0 + r) * KVSTR + h * 64 + d);
                    *(uint2*)&vv = uu;
                    t0 = vv[0]; t1 = vv[1]; t2 = vv[2]; t3 = vv[3];
                }
                Vt[d + 0][r] = t0; Vt[d + 1][r] = t1;
                Vt[d + 2][r] = t2; Vt[d + 3][r] = t3;
            }
            __syncthreads();

            f32x4 sc[4];
            #pragma unroll
            for (int t = 0; t < 4; ++t) {
                bf16x8 b0 = *(const bf16x8*)&Ks[t * 16 + l16][quad * 8];
                bf16x8 b1 = *(const bf16x8*)&Ks[t * 16 + l16][32 + quad * 8];
                f32x4 z = {};
                z = __builtin_amdgcn_mfma_f32_16x16x32_bf16(qf[0], b0, z, 0, 0, 0);
                z = __builtin_amdgcn_mfma_f32_16x16x32_bf16(qf[1], b1, z, 0, 0, 0);
                sc[t] = z;
            }

            float sv[4][4];
            #pragma unroll
            for (int t = 0; t < 4; ++t) {
                const bool ok = (c0 + t * 16 + l16) < kend;
                #pragma unroll
                for (int r = 0; r < 4; ++r)
                    sv[t][r] = ok ? sc[t][r] * SCALER : -1e30f;
            }

            #pragma unroll
            for (int r = 0; r < 4; ++r) {
                float mx = fmaxf(fmaxf(sv[0][r], sv[1][r]), fmaxf(sv[2][r], sv[3][r]));
                mx = fmaxf(mx, __shfl_xor(mx, 1));
                mx = fmaxf(mx, __shfl_xor(mx, 2));
                mx = fmaxf(mx, __shfl_xor(mx, 4));
                mx = fmaxf(mx, __shfl_xor(mx, 8));
                const float mn = fmaxf(m[r], mx);
                const float alpha = __expf(m[r] - mn);
                m[r] = mn;
                float rs = 0.f;
                #pragma unroll
                for (int t = 0; t < 4; ++t) {
                    const float p = __expf(sv[t][r] - mn);
                    sv[t][r] = p;
                    rs += p;
                }
                rs += __shfl_xor(rs, 1);
                rs += __shfl_xor(rs, 2);
                rs += __shfl_xor(rs, 4);
                rs += __shfl_xor(rs, 8);
                l[r] = l[r] * alpha + rs;
                #pragma unroll
                for (int dt = 0; dt < 4; ++dt) acc[dt][r] *= alpha;
            }

            #pragma unroll
            for (int t = 0; t < 4; ++t)
                #pragma unroll
                for (int r = 0; r < 4; ++r)
                    Ps[wave][quad * 4 + r][t * 16 + l16] = (__bf16)sv[t][r];
            __syncthreads();

            #pragma unroll
            for (int ks = 0; ks < 2; ++ks) {
                bf16x8 pa = *(const bf16x8*)&Ps[wave][l16][ks * 32 + quad * 8];
                #pragma unroll
                for (int dt = 0; dt < 4; ++dt) {
                    bf16x8 vbf = *(const bf16x8*)&Vt[dt * 16 + l16][ks * 32 + quad * 8];
                    acc[dt] = __builtin_amdgcn_mfma_f32_16x16x32_bf16(pa, vbf, acc[dt], 0, 0, 0);
                }
            }
        }

        float inv[4];
        #pragma unroll
        for (int r = 0; r < 4; ++r) inv[r] = 1.f / l[r];
        #pragma unroll
        for (int dt = 0; dt < 4; ++dt) {
            #pragma unroll
            for (int r = 0; r < 4; ++r) {
                const int row = qt + wave * 16 + quad * 4 + r;
                if (row < qend)
                    wv[(size_t)row * DV + h * 64 + dt * 16 + l16] =
                        __float2bfloat16(acc[dt][r] * inv[r]);
            }
        }
    }
}

// ---------------------------------------------------------------------------
extern "C" void kernel_launch(void* const* d_in, const int* in_sizes, int n_in,
                              void* d_out, int out_size, void* d_ws, size_t ws_size,
                              hipStream_t stream)
{
    const float* A     = (const float*)d_in[0];
    const float* B0    = (const float*)d_in[1];
    const int*   seg_q = (const int*)  d_in[2];
    const int*   seg_kv= (const int*)  d_in[3];
    const float* Wq    = (const float*)d_in[4];
    const float* bq    = (const float*)d_in[5];
    const float* Wk    = (const float*)d_in[6];
    const float* bk    = (const float*)d_in[7];
    const float* Wv    = (const float*)d_in[8];
    const float* bv    = (const float*)d_in[9];
    const float* Wf    = (const float*)d_in[10];
    const float* bf    = (const float*)d_in[11];
    float* out = (float*)d_out;

    // Workspace (bf16 elems), 29.6 MB total; all offsets 16B-aligned
    __hip_bfloat16* B0bf = (__hip_bfloat16*)d_ws;                 // 2048*1056
    __hip_bfloat16* Wqt  = B0bf + (size_t)TOTAL_KV * KVIN_P;      // 1024*1024
    __hip_bfloat16* Wkt  = Wqt  + (size_t)QIN * DQK;              // 1024*1056  \ fused
    __hip_bfloat16* Wvt  = Wkt  + (size_t)DQK * KVIN_P;           // 1024*1056  / [2048][1056]
    __hip_bfloat16* Wft  = Wvt  + (size_t)DV * KVIN_P;            // 1024*1024
    __hip_bfloat16* Abf  = Wft  + (size_t)DV * QIN;               // 2048*1024
    __hip_bfloat16* qb   = Abf  + (size_t)TOTAL_Q * QIN;          // 2048*1024
    __hip_bfloat16* kvb  = qb   + (size_t)TOTAL_Q * DQK;          // 2048*2048 fused [k|v]
    __hip_bfloat16* wvb  = Abf;  // alias: Abf dead after grouped QKV GEMM

    const dim3 b256(256);

    // 1) fused prep: casts + weight transposes
    prep_k<<<dim3(8320), b256, 0, stream>>>(A, B0, Wq, Wk, Wv, Wf,
                                            Abf, B0bf, Wqt, Wkt, Wvt, Wft);

    // 2) grouped Q + KV projections (384 blocks: 128 Q + 256 KV)
    gemm_qkv<<<dim3(384), b256, 0, stream>>>(Abf, Wqt, bq, qb,
                                             B0bf, Wkt, bk, bv, kvb);

    // 3) attention: block per (segment, head)
    attn_mfma<<<dim3(32 * 16), b256, 0, stream>>>(qb, kvb, kvb + 1024, seg_q, seg_kv, wvb);

    // 4) output projection (fp32 out)
    gemm_out<<<dim3(QIN / 64, TOTAL_Q / 128), b256, 0, stream>>>(
        wvb, Wft, bf, out, TOTAL_Q, QIN, DV);
}

// Round 6
// 173.048 us; speedup vs baseline: 4.4080x; 1.0028x over previous
//
#include <hip/hip_runtime.h>
#include <hip/hip_bf16.h>
#include <math.h>

#define TOTAL_Q   2048
#define TOTAL_KV  2048
#define QIN       1024
#define KVIN      1033
#define KVIN_P    1056      // KVIN padded to multiple of 32 (zero-filled)
#define DQK       1024
#define DV        1024
#define KVSTR     2048      // fused [k|v] row stride
#define SCALER    0.125f    // 1/sqrt(64)

typedef __bf16 bf16x8 __attribute__((ext_vector_type(8)));
typedef float  f32x4  __attribute__((ext_vector_type(4)));

// async global->LDS, 16 B per lane; LDS dest = wave-uniform base + lane*16
__device__ __forceinline__ void glds16(const __hip_bfloat16* g, __bf16* l)
{
    __builtin_amdgcn_global_load_lds(
        (const __attribute__((address_space(1))) void*)g,
        (__attribute__((address_space(3))) void*)l,
        16, 0, 0);
}

// ---------------------------------------------------------------------------
// Fused prep: one launch, flat grid, block ranges:
//   [0,2048)       : cast A fp32->bf16            (2048x1024, 4 elem/thread)
//   [2048,4160)    : cast+pad B0 -> [2048][1056]
//   [4160,6208)    : transpose Wq|Wf  [1024][1024] -> [1024][1024]
//   [6208,8320)    : transpose Wk|Wv  [1033][1024] -> [1024][1056]
//   [8320,10368)   : init out[r][c] = bf[c]  (split-K out-proj accumulates on top)
// ---------------------------------------------------------------------------
__global__ __launch_bounds__(256)
void prep_k(const float* __restrict__ A,  const float* __restrict__ B0,
            const float* __restrict__ Wq, const float* __restrict__ Wk,
            const float* __restrict__ Wv, const float* __restrict__ Wf,
            const float* __restrict__ bf,
            __hip_bfloat16* __restrict__ Abf, __hip_bfloat16* __restrict__ B0bf,
            __hip_bfloat16* __restrict__ Wqt, __hip_bfloat16* __restrict__ Wkt,
            __hip_bfloat16* __restrict__ Wvt, __hip_bfloat16* __restrict__ Wft,
            float* __restrict__ outp)
{
    const int b   = blockIdx.x;
    const int tid = threadIdx.x;

    if (b < 2048) {                       // ---- cast A
        int i = (b * 256 + tid) * 4;
        float4 f = *(const float4*)(A + i);
        __hip_bfloat16 o[4] = { __float2bfloat16(f.x), __float2bfloat16(f.y),
                                __float2bfloat16(f.z), __float2bfloat16(f.w) };
        *(uint2*)(Abf + i) = *(const uint2*)o;
        return;
    }
    if (b < 4160) {                       // ---- cast+pad B0
        int idx = ((b - 2048) * 256 + tid) * 4;       // padded-elem index
        int r = idx / KVIN_P, c = idx - r * KVIN_P;   // 4-groups never cross rows
        __hip_bfloat16 o[4];
        #pragma unroll
        for (int j = 0; j < 4; ++j)
            o[j] = __float2bfloat16((c + j < KVIN) ? B0[(size_t)r * KVIN + c + j] : 0.f);
        *(uint2*)(B0bf + idx) = *(const uint2*)o;
        return;
    }
    if (b >= 8320) {                      // ---- out = bias (broadcast rows)
        int idx = ((b - 8320) * 256 + tid) * 4;
        int c = idx & 1023;
        float4 o = { bf[c], bf[c + 1], bf[c + 2], bf[c + 3] };
        *(float4*)(outp + idx) = o;
        return;
    }

    // ---- transposes: W[K][1024] -> Wt[1024][Kp], zero-fill k >= K
    const float* W; __hip_bfloat16* Wt; int K, Kp, k0, n0;
    if (b < 6208) {
        int z = b - 4160;                 // 2 x 1024 blocks, 32x32 tiles
        W  = (z >= 1024) ? Wf : Wq;
        Wt = (z >= 1024) ? Wft : Wqt;
        K = 1024; Kp = 1024;
        int rem = z & 1023;
        k0 = (rem & 31) * 32; n0 = (rem >> 5) * 32;
    } else {
        int z = b - 6208;                 // 2 x 1056 blocks (33 k-tiles x 32 n-tiles)
        W  = (z >= 1056) ? Wv : Wk;
        Wt = (z >= 1056) ? Wvt : Wkt;
        K = KVIN; Kp = KVIN_P;
        int rem = (z >= 1056) ? z - 1056 : z;
        k0 = (rem % 33) * 32; n0 = (rem / 33) * 32;
    }
    const int tx = tid & 31, ty = tid >> 5;   // (32,8)
    __shared__ float tile[32][33];
    #pragma unroll
    for (int i = 0; i < 4; ++i) {
        int k = k0 + ty + i * 8;
        tile[ty + i * 8][tx] = (k < K) ? W[(size_t)k * 1024 + n0 + tx] : 0.f;
    }
    __syncthreads();
    #pragma unroll
    for (int i = 0; i < 4; ++i) {
        int n = n0 + ty + i * 8;
        Wt[(size_t)n * Kp + k0 + tx] = __float2bfloat16(tile[tx][ty + i * 8]);
    }
}

// ---------------------------------------------------------------------------
// Grouped Q + fused-KV projection. BM=128, BN=64, BK=32 -> 768 blocks (3/CU).
//   blocks [0,256)   : Q-proj  (2048x1024 @ K=1024), 16x16 grid
//   blocks [256,768) : KV-proj (2048x2048 @ K=1056, bias split at 1024), 32x16
// 4 waves, wave-tile 64x32 (4x2 MFMAs of 16x16x32; 8 MFMA : 6 ds_read_b128).
// Staging: 12 glds16 chunks (1 KB = 16 rows x 32 elems), 3 per wave. LDS 12 KB
// unpadded (lane-order contiguous as global_load_lds requires).
// ---------------------------------------------------------------------------
__global__ __launch_bounds__(256)
void gemm_qkv(const __hip_bfloat16* __restrict__ Abf,
              const __hip_bfloat16* __restrict__ Wqt,
              const float* __restrict__ bq,
              __hip_bfloat16* __restrict__ qb,
              const __hip_bfloat16* __restrict__ B0bf,
              const __hip_bfloat16* __restrict__ Wkvt,
              const float* __restrict__ bk, const float* __restrict__ bv,
              __hip_bfloat16* __restrict__ kvb)
{
    __shared__ __bf16 As[128 * 32];   // 8 KB
    __shared__ __bf16 Bs[64 * 32];    // 4 KB

    int b = blockIdx.x;
    const __hip_bfloat16 *Ag, *Btg; const float *bias0, *bias1;
    __hip_bfloat16* C; int N, K, bx, by;
    if (b < 256) {        // Q: 16 cols x 16 rows
        Ag = Abf; Btg = Wqt; bias0 = bq; bias1 = bq; C = qb;
        N = 1024; K = 1024; bx = b & 15; by = b >> 4;
    } else {              // KV: 32 cols x 16 rows
        b -= 256;
        Ag = B0bf; Btg = Wkvt; bias0 = bk; bias1 = bv; C = kvb;
        N = 2048; K = KVIN_P; bx = b & 31; by = b >> 5;
    }
    const int row0 = by * 128, col0 = bx * 64;

    const int tid  = threadIdx.x;
    const int wave = tid >> 6, lane = tid & 63;
    const int quad = lane >> 4, l16 = lane & 15;
    const int wm = (wave >> 1) * 64, wn = (wave & 1) * 32;

    // staging: chunk = 16 rows x 32 elems; lane covers row cr, 8-col group cc
    const int cr = lane >> 2;
    const int cc = (lane & 3) * 8;

    // wave w stages chunks w*3 .. w*3+2 (0..7 -> A rows, 8..11 -> B rows)
    const __hip_bfloat16* gsrc[3];
    __bf16* ldst[3];
    #pragma unroll
    for (int i = 0; i < 3; ++i) {
        int c = wave * 3 + i;
        if (c < 8) {
            gsrc[i] = Ag  + (size_t)(row0 + c * 16 + cr) * K + cc;
            ldst[i] = &As[c * 512];
        } else {
            gsrc[i] = Btg + (size_t)(col0 + (c - 8) * 16 + cr) * K + cc;
            ldst[i] = &Bs[(c - 8) * 512];
        }
    }

    f32x4 acc[4][2] = {};

    for (int k0 = 0; k0 < K; k0 += 32) {
        #pragma unroll
        for (int i = 0; i < 3; ++i)
            glds16(gsrc[i] + k0, ldst[i]);
        __syncthreads();

        bf16x8 af[4], bfr[2];
        #pragma unroll
        for (int mi = 0; mi < 4; ++mi)
            af[mi] = *(const bf16x8*)&As[(wm + mi * 16 + l16) * 32 + quad * 8];
        #pragma unroll
        for (int ni = 0; ni < 2; ++ni)
            bfr[ni] = *(const bf16x8*)&Bs[(wn + ni * 16 + l16) * 32 + quad * 8];

        #pragma unroll
        for (int mi = 0; mi < 4; ++mi)
            #pragma unroll
            for (int ni = 0; ni < 2; ++ni)
                acc[mi][ni] = __builtin_amdgcn_mfma_f32_16x16x32_bf16(
                    af[mi], bfr[ni], acc[mi][ni], 0, 0, 0);
        __syncthreads();
    }

    #pragma unroll
    for (int mi = 0; mi < 4; ++mi) {
        #pragma unroll
        for (int ni = 0; ni < 2; ++ni) {
            const int col = col0 + wn + ni * 16 + l16;
            const float bia = (col < 1024) ? bias0[col] : bias1[col - 1024];
            #pragma unroll
            for (int r = 0; r < 4; ++r) {
                const int row = row0 + wm + mi * 16 + quad * 4 + r;
                C[(size_t)row * N + col] = __float2bfloat16(acc[mi][ni][r] + bia);
            }
        }
    }
}

// ---------------------------------------------------------------------------
// Output projection, split-K=2: 512 blocks (2/CU). Block (bx,by,kz) computes
// the partial C-tile over K rows [kz*512, kz*512+512) and atomically adds into
// out (pre-initialized with bias by prep_k). BM=128, BN=64, BK=32.
// ---------------------------------------------------------------------------
__global__ __launch_bounds__(256)
void gemm_out(const __hip_bfloat16* __restrict__ A,
              const __hip_bfloat16* __restrict__ Bt,
              float* __restrict__ C,
              int M, int N, int K)   // K = full depth (1024)
{
    __shared__ __bf16 As[128 * 32];
    __shared__ __bf16 Bs[64 * 32];

    const int tid  = threadIdx.x;
    const int wave = tid >> 6, lane = tid & 63;
    const int quad = lane >> 4, l16 = lane & 15;
    const int wm = (wave >> 1) * 64;
    const int wn = (wave & 1) * 32;
    const int row0 = blockIdx.y * 128, col0 = blockIdx.x * 64;
    const int kz0 = blockIdx.z * (K / 2), kz1 = kz0 + K / 2;

    const int cr = lane >> 2;
    const int cc = (lane & 3) * 8;

    const __hip_bfloat16* gsrc[3];
    __bf16* ldst[3];
    #pragma unroll
    for (int i = 0; i < 3; ++i) {
        int c = wave * 3 + i;
        if (c < 8) {
            gsrc[i] = A  + (size_t)(row0 + c * 16 + cr) * K + cc;
            ldst[i] = &As[c * 512];
        } else {
            gsrc[i] = Bt + (size_t)(col0 + (c - 8) * 16 + cr) * K + cc;
            ldst[i] = &Bs[(c - 8) * 512];
        }
    }

    f32x4 acc[4][2] = {};

    for (int k0 = kz0; k0 < kz1; k0 += 32) {
        #pragma unroll
        for (int i = 0; i < 3; ++i)
            glds16(gsrc[i] + k0, ldst[i]);
        __syncthreads();

        bf16x8 af[4], bfr[2];
        #pragma unroll
        for (int mi = 0; mi < 4; ++mi)
            af[mi] = *(const bf16x8*)&As[(wm + mi * 16 + l16) * 32 + quad * 8];
        #pragma unroll
        for (int ni = 0; ni < 2; ++ni)
            bfr[ni] = *(const bf16x8*)&Bs[(wn + ni * 16 + l16) * 32 + quad * 8];

        #pragma unroll
        for (int mi = 0; mi < 4; ++mi)
            #pragma unroll
            for (int ni = 0; ni < 2; ++ni)
                acc[mi][ni] = __builtin_amdgcn_mfma_f32_16x16x32_bf16(
                    af[mi], bfr[ni], acc[mi][ni], 0, 0, 0);
        __syncthreads();
    }

    #pragma unroll
    for (int mi = 0; mi < 4; ++mi) {
        #pragma unroll
        for (int ni = 0; ni < 2; ++ni) {
            const int col = col0 + wn + ni * 16 + l16;
            #pragma unroll
            for (int r = 0; r < 4; ++r) {
                const int row = row0 + wm + mi * 16 + quad * 4 + r;
                atomicAdd(&C[(size_t)row * N + col], acc[mi][ni][r]);
            }
        }
    }
}

// ---------------------------------------------------------------------------
// MFMA flash attention over ragged segments (unchanged from R3/R4/R5).
// ---------------------------------------------------------------------------
#define CH 64

__global__ __launch_bounds__(256)
void attn_mfma(const __hip_bfloat16* __restrict__ qg,
               const __hip_bfloat16* __restrict__ kg,   // kvb
               const __hip_bfloat16* __restrict__ vg,   // kvb + 1024
               const int* __restrict__ seg_q, const int* __restrict__ seg_kv,
               __hip_bfloat16* __restrict__ wv)
{
    const int h = blockIdx.x & 15;
    const int s = blockIdx.x >> 4;

    __shared__ int sb[4];
    __shared__ __bf16 Ks[CH][72];
    __shared__ __bf16 Vt[64][CH + 8];
    __shared__ __bf16 Ps[4][16][CH + 8];

    if (threadIdx.x == 0) {
        int lo, hi;
        lo = 0; hi = TOTAL_Q;
        while (lo < hi) { int m = (lo + hi) >> 1; if (seg_q[m] <  s) lo = m + 1; else hi = m; }
        sb[0] = lo;
        hi = TOTAL_Q;
        while (lo < hi) { int m = (lo + hi) >> 1; if (seg_q[m] <= s) lo = m + 1; else hi = m; }
        sb[1] = lo;
        lo = 0; hi = TOTAL_KV;
        while (lo < hi) { int m = (lo + hi) >> 1; if (seg_kv[m] <  s) lo = m + 1; else hi = m; }
        sb[2] = lo;
        hi = TOTAL_KV;
        while (lo < hi) { int m = (lo + hi) >> 1; if (seg_kv[m] <= s) lo = m + 1; else hi = m; }
        sb[3] = lo;
    }
    __syncthreads();
    const int qbeg = sb[0], qend = sb[1], kbeg = sb[2], kend = sb[3];

    const int tid  = threadIdx.x;
    const int wave = tid >> 6, lane = tid & 63;
    const int quad = lane >> 4, l16 = lane & 15;

    for (int qt = qbeg; qt < qend; qt += 64) {
        const int qrow = qt + wave * 16 + l16;
        const int qrc  = min(qrow, qend - 1);
        bf16x8 qf[2];
        qf[0] = *(const bf16x8*)(qg + (size_t)qrc * DQK + h * 64 + quad * 8);
        qf[1] = *(const bf16x8*)(qg + (size_t)qrc * DQK + h * 64 + 32 + quad * 8);

        float m[4]  = { -1e30f, -1e30f, -1e30f, -1e30f };
        float l[4]  = { 0.f, 0.f, 0.f, 0.f };
        f32x4 acc[4] = {};

        for (int c0 = kbeg; c0 < kend; c0 += CH) {
            const int cl = min(CH, kend - c0);
            __syncthreads();

            #pragma unroll
            for (int it = 0; it < 2; ++it) {
                int e = (it * 256 + tid) * 8;
                int r = e >> 6, d = e & 63;
                bf16x8 z = {};
                if (r < cl)
                    z = *(const bf16x8*)(kg + (size_t)(c0 + r) * KVSTR + h * 64 + d);
                *(bf16x8*)&Ks[r][d] = z;
            }
            #pragma unroll
            for (int it = 0; it < 4; ++it) {
                int e = (it * 256 + tid) * 4;
                int r = e >> 6, d = e & 63;
                __bf16 t0 = 0, t1 = 0, t2 = 0, t3 = 0;
                if (r < cl) {
                    bf16x8 vv;
                    uint2 uu = *(const uint2*)(vg + (size_t)(c0 + r) * KVSTR + h * 64 + d);
                    *(uint2*)&vv = uu;
                    t0 = vv[0]; t1 = vv[1]; t2 = vv[2]; t3 = vv[3];
                }
                Vt[d + 0][r] = t0; Vt[d + 1][r] = t1;
                Vt[d + 2][r] = t2; Vt[d + 3][r] = t3;
            }
            __syncthreads();

            f32x4 sc[4];
            #pragma unroll
            for (int t = 0; t < 4; ++t) {
                bf16x8 b0 = *(const bf16x8*)&Ks[t * 16 + l16][quad * 8];
                bf16x8 b1 = *(const bf16x8*)&Ks[t * 16 + l16][32 + quad * 8];
                f32x4 z = {};
                z = __builtin_amdgcn_mfma_f32_16x16x32_bf16(qf[0], b0, z, 0, 0, 0);
                z = __builtin_amdgcn_mfma_f32_16x16x32_bf16(qf[1], b1, z, 0, 0, 0);
                sc[t] = z;
            }

            float sv[4][4];
            #pragma unroll
            for (int t = 0; t < 4; ++t) {
                const bool ok = (c0 + t * 16 + l16) < kend;
                #pragma unroll
                for (int r = 0; r < 4; ++r)
                    sv[t][r] = ok ? sc[t][r] * SCALER : -1e30f;
            }

            #pragma unroll
            for (int r = 0; r < 4; ++r) {
                float mx = fmaxf(fmaxf(sv[0][r], sv[1][r]), fmaxf(sv[2][r], sv[3][r]));
                mx = fmaxf(mx, __shfl_xor(mx, 1));
                mx = fmaxf(mx, __shfl_xor(mx, 2));
                mx = fmaxf(mx, __shfl_xor(mx, 4));
                mx = fmaxf(mx, __shfl_xor(mx, 8));
                const float mn = fmaxf(m[r], mx);
                const float alpha = __expf(m[r] - mn);
                m[r] = mn;
                float rs = 0.f;
                #pragma unroll
                for (int t = 0; t < 4; ++t) {
                    const float p = __expf(sv[t][r] - mn);
                    sv[t][r] = p;
                    rs += p;
                }
                rs += __shfl_xor(rs, 1);
                rs += __shfl_xor(rs, 2);
                rs += __shfl_xor(rs, 4);
                rs += __shfl_xor(rs, 8);
                l[r] = l[r] * alpha + rs;
                #pragma unroll
                for (int dt = 0; dt < 4; ++dt) acc[dt][r] *= alpha;
            }

            #pragma unroll
            for (int t = 0; t < 4; ++t)
                #pragma unroll
                for (int r = 0; r < 4; ++r)
                    Ps[wave][quad * 4 + r][t * 16 + l16] = (__bf16)sv[t][r];
            __syncthreads();

            #pragma unroll
            for (int ks = 0; ks < 2; ++ks) {
                bf16x8 pa = *(const bf16x8*)&Ps[wave][l16][ks * 32 + quad * 8];
                #pragma unroll
                for (int dt = 0; dt < 4; ++dt) {
                    bf16x8 vbf = *(const bf16x8*)&Vt[dt * 16 + l16][ks * 32 + quad * 8];
                    acc[dt] = __builtin_amdgcn_mfma_f32_16x16x32_bf16(pa, vbf, acc[dt], 0, 0, 0);
                }
            }
        }

        float inv[4];
        #pragma unroll
        for (int r = 0; r < 4; ++r) inv[r] = 1.f / l[r];
        #pragma unroll
        for (int dt = 0; dt < 4; ++dt) {
            #pragma unroll
            for (int r = 0; r < 4; ++r) {
                const int row = qt + wave * 16 + quad * 4 + r;
                if (row < qend)
                    wv[(size_t)row * DV + h * 64 + dt * 16 + l16] =
                        __float2bfloat16(acc[dt][r] * inv[r]);
            }
        }
    }
}

// ---------------------------------------------------------------------------
extern "C" void kernel_launch(void* const* d_in, const int* in_sizes, int n_in,
                              void* d_out, int out_size, void* d_ws, size_t ws_size,
                              hipStream_t stream)
{
    const float* A     = (const float*)d_in[0];
    const float* B0    = (const float*)d_in[1];
    const int*   seg_q = (const int*)  d_in[2];
    const int*   seg_kv= (const int*)  d_in[3];
    const float* Wq    = (const float*)d_in[4];
    const float* bq    = (const float*)d_in[5];
    const float* Wk    = (const float*)d_in[6];
    const float* bk    = (const float*)d_in[7];
    const float* Wv    = (const float*)d_in[8];
    const float* bv    = (const float*)d_in[9];
    const float* Wf    = (const float*)d_in[10];
    const float* bf    = (const float*)d_in[11];
    float* out = (float*)d_out;

    // Workspace (bf16 elems), 29.6 MB total; all offsets 16B-aligned
    __hip_bfloat16* B0bf = (__hip_bfloat16*)d_ws;                 // 2048*1056
    __hip_bfloat16* Wqt  = B0bf + (size_t)TOTAL_KV * KVIN_P;      // 1024*1024
    __hip_bfloat16* Wkt  = Wqt  + (size_t)QIN * DQK;              // 1024*1056  \ fused
    __hip_bfloat16* Wvt  = Wkt  + (size_t)DQK * KVIN_P;           // 1024*1056  / [2048][1056]
    __hip_bfloat16* Wft  = Wvt  + (size_t)DV * KVIN_P;            // 1024*1024
    __hip_bfloat16* Abf  = Wft  + (size_t)DV * QIN;               // 2048*1024
    __hip_bfloat16* qb   = Abf  + (size_t)TOTAL_Q * QIN;          // 2048*1024
    __hip_bfloat16* kvb  = qb   + (size_t)TOTAL_Q * DQK;          // 2048*2048 fused [k|v]
    __hip_bfloat16* wvb  = Abf;  // alias: Abf dead after grouped QKV GEMM

    const dim3 b256(256);

    // 1) fused prep: casts + weight transposes + out-bias init
    prep_k<<<dim3(10368), b256, 0, stream>>>(A, B0, Wq, Wk, Wv, Wf, bf,
                                             Abf, B0bf, Wqt, Wkt, Wvt, Wft, out);

    // 2) grouped Q + KV projections (768 blocks: 256 Q + 512 KV; 3 blocks/CU)
    gemm_qkv<<<dim3(768), b256, 0, stream>>>(Abf, Wqt, bq, qb,
                                             B0bf, Wkt, bk, bv, kvb);

    // 3) attention: block per (segment, head)
    attn_mfma<<<dim3(32 * 16), b256, 0, stream>>>(qb, kvb, kvb + 1024, seg_q, seg_kv, wvb);

    // 4) output projection, split-K=2, atomic accumulate onto bias-initialized out
    gemm_out<<<dim3(QIN / 64, TOTAL_Q / 128, 2), b256, 0, stream>>>(
        wvb, Wft, out, TOTAL_Q, QIN, DV);
}

// Round 8
// 170.321 us; speedup vs baseline: 4.4785x; 1.0160x over previous
//
#include <hip/hip_runtime.h>
#include <hip/hip_bf16.h>
#include <math.h>

#define TOTAL_Q   2048
#define TOTAL_KV  2048
#define QIN       1024
#define KVIN      1033
#define KVIN_P    1056      // KVIN padded to multiple of 32 (zero-filled)
#define DQK       1024
#define DV        1024
#define KVSTR     2048      // fused [k|v] row stride
#define SCALER    0.125f    // 1/sqrt(64)

typedef __bf16 bf16x8 __attribute__((ext_vector_type(8)));
typedef float  f32x4  __attribute__((ext_vector_type(4)));

// async global->LDS, 16 B per lane; LDS dest = wave-uniform base + lane*16
__device__ __forceinline__ void glds16(const __hip_bfloat16* g, __bf16* l)
{
    __builtin_amdgcn_global_load_lds(
        (const __attribute__((address_space(1))) void*)g,
        (__attribute__((address_space(3))) void*)l,
        16, 0, 0);
}

// ---------------------------------------------------------------------------
// Fused prep (unchanged from R6): one launch, flat grid, block ranges:
//   [0,2048)       : cast A fp32->bf16
//   [2048,4160)    : cast+pad B0 -> [2048][1056]
//   [4160,6208)    : transpose Wq|Wf
//   [6208,8320)    : transpose Wk|Wv
//   [8320,10368)   : init out[r][c] = bf[c]
// ---------------------------------------------------------------------------
__global__ __launch_bounds__(256)
void prep_k(const float* __restrict__ A,  const float* __restrict__ B0,
            const float* __restrict__ Wq, const float* __restrict__ Wk,
            const float* __restrict__ Wv, const float* __restrict__ Wf,
            const float* __restrict__ bf,
            __hip_bfloat16* __restrict__ Abf, __hip_bfloat16* __restrict__ B0bf,
            __hip_bfloat16* __restrict__ Wqt, __hip_bfloat16* __restrict__ Wkt,
            __hip_bfloat16* __restrict__ Wvt, __hip_bfloat16* __restrict__ Wft,
            float* __restrict__ outp)
{
    const int b   = blockIdx.x;
    const int tid = threadIdx.x;

    if (b < 2048) {                       // ---- cast A
        int i = (b * 256 + tid) * 4;
        float4 f = *(const float4*)(A + i);
        __hip_bfloat16 o[4] = { __float2bfloat16(f.x), __float2bfloat16(f.y),
                                __float2bfloat16(f.z), __float2bfloat16(f.w) };
        *(uint2*)(Abf + i) = *(const uint2*)o;
        return;
    }
    if (b < 4160) {                       // ---- cast+pad B0
        int idx = ((b - 2048) * 256 + tid) * 4;
        int r = idx / KVIN_P, c = idx - r * KVIN_P;
        __hip_bfloat16 o[4];
        #pragma unroll
        for (int j = 0; j < 4; ++j)
            o[j] = __float2bfloat16((c + j < KVIN) ? B0[(size_t)r * KVIN + c + j] : 0.f);
        *(uint2*)(B0bf + idx) = *(const uint2*)o;
        return;
    }
    if (b >= 8320) {                      // ---- out = bias (broadcast rows)
        int idx = ((b - 8320) * 256 + tid) * 4;
        int c = idx & 1023;
        float4 o = { bf[c], bf[c + 1], bf[c + 2], bf[c + 3] };
        *(float4*)(outp + idx) = o;
        return;
    }

    // ---- transposes: W[K][1024] -> Wt[1024][Kp], zero-fill k >= K
    const float* W; __hip_bfloat16* Wt; int K, Kp, k0, n0;
    if (b < 6208) {
        int z = b - 4160;
        W  = (z >= 1024) ? Wf : Wq;
        Wt = (z >= 1024) ? Wft : Wqt;
        K = 1024; Kp = 1024;
        int rem = z & 1023;
        k0 = (rem & 31) * 32; n0 = (rem >> 5) * 32;
    } else {
        int z = b - 6208;
        W  = (z >= 1056) ? Wv : Wk;
        Wt = (z >= 1056) ? Wvt : Wkt;
        K = KVIN; Kp = KVIN_P;
        int rem = (z >= 1056) ? z - 1056 : z;
        k0 = (rem % 33) * 32; n0 = (rem / 33) * 32;
    }
    const int tx = tid & 31, ty = tid >> 5;   // (32,8)
    __shared__ float tile[32][33];
    #pragma unroll
    for (int i = 0; i < 4; ++i) {
        int k = k0 + ty + i * 8;
        tile[ty + i * 8][tx] = (k < K) ? W[(size_t)k * 1024 + n0 + tx] : 0.f;
    }
    __syncthreads();
    #pragma unroll
    for (int i = 0; i < 4; ++i) {
        int n = n0 + ty + i * 8;
        Wt[(size_t)n * Kp + k0 + tx] = __float2bfloat16(tile[tx][ty + i * 8]);
    }
}

// ---------------------------------------------------------------------------
// XOR-swizzled LDS tile layout for glds16-staged GEMMs.
// LDS tile row = 32 bf16 (64 B) split in four 16 B slots. Slot s of row r
// holds global k-group g = s ^ ((r>>1)&3). Staging lane (chunk = 16 rows):
// row cr = lane>>2, slot = lane&3 -> fetch global group (lane&3)^((lane>>3)&3).
// Fragment read for logical (row, kgroup=quad): slot = quad ^ ((row>>1)&3).
// Bank effect: fragment ds_read_b128 goes from 8-lane to 2-lane bank aliasing
// (free per m136). Coalescing unchanged (permutation within a 64 B row).
// ---------------------------------------------------------------------------
__device__ __forceinline__ int stage_cc(int lane)   // global elem offset (x8)
{
    return (((lane & 3) ^ ((lane >> 3) & 3)) * 8);
}
__device__ __forceinline__ int frag_off(int row, int quad)  // LDS elem offset
{
    return row * 32 + ((quad ^ ((row >> 1) & 3)) * 8);
}

// ---------------------------------------------------------------------------
// Grouped Q + fused-KV projection. BM=128, BN=64, BK=32 -> 768 blocks (3/CU).
//   blocks [0,256)   : Q-proj  (2048x1024 @ K=1024)
//   blocks [256,768) : KV-proj (2048x2048 @ K=1056, bias split at 1024)
// 4 waves, wave-tile 64x32. Staging: 12 glds16 chunks, 3 per wave, swizzled.
// ---------------------------------------------------------------------------
__global__ __launch_bounds__(256)
void gemm_qkv(const __hip_bfloat16* __restrict__ Abf,
              const __hip_bfloat16* __restrict__ Wqt,
              const float* __restrict__ bq,
              __hip_bfloat16* __restrict__ qb,
              const __hip_bfloat16* __restrict__ B0bf,
              const __hip_bfloat16* __restrict__ Wkvt,
              const float* __restrict__ bk, const float* __restrict__ bv,
              __hip_bfloat16* __restrict__ kvb)
{
    __shared__ __bf16 As[128 * 32];   // 8 KB
    __shared__ __bf16 Bs[64 * 32];    // 4 KB

    int b = blockIdx.x;
    const __hip_bfloat16 *Ag, *Btg; const float *bias0, *bias1;
    __hip_bfloat16* C; int N, K, bx, by;
    if (b < 256) {        // Q: 16 cols x 16 rows
        Ag = Abf; Btg = Wqt; bias0 = bq; bias1 = bq; C = qb;
        N = 1024; K = 1024; bx = b & 15; by = b >> 4;
    } else {              // KV: 32 cols x 16 rows
        b -= 256;
        Ag = B0bf; Btg = Wkvt; bias0 = bk; bias1 = bv; C = kvb;
        N = 2048; K = KVIN_P; bx = b & 31; by = b >> 5;
    }
    const int row0 = by * 128, col0 = bx * 64;

    const int tid  = threadIdx.x;
    const int wave = tid >> 6, lane = tid & 63;
    const int quad = lane >> 4, l16 = lane & 15;
    const int wm = (wave >> 1) * 64, wn = (wave & 1) * 32;

    const int cr = lane >> 2;          // staging row within chunk
    const int cc = stage_cc(lane);     // swizzled global elem offset

    const __hip_bfloat16* gsrc[3];
    __bf16* ldst[3];
    #pragma unroll
    for (int i = 0; i < 3; ++i) {
        int c = wave * 3 + i;
        if (c < 8) {
            gsrc[i] = Ag  + (size_t)(row0 + c * 16 + cr) * K + cc;
            ldst[i] = &As[c * 512];
        } else {
            gsrc[i] = Btg + (size_t)(col0 + (c - 8) * 16 + cr) * K + cc;
            ldst[i] = &Bs[(c - 8) * 512];
        }
    }

    f32x4 acc[4][2] = {};

    for (int k0 = 0; k0 < K; k0 += 32) {
        #pragma unroll
        for (int i = 0; i < 3; ++i)
            glds16(gsrc[i] + k0, ldst[i]);
        __syncthreads();

        bf16x8 af[4], bfr[2];
        #pragma unroll
        for (int mi = 0; mi < 4; ++mi)
            af[mi] = *(const bf16x8*)&As[frag_off(wm + mi * 16 + l16, quad)];
        #pragma unroll
        for (int ni = 0; ni < 2; ++ni)
            bfr[ni] = *(const bf16x8*)&Bs[frag_off(wn + ni * 16 + l16, quad)];

        #pragma unroll
        for (int mi = 0; mi < 4; ++mi)
            #pragma unroll
            for (int ni = 0; ni < 2; ++ni)
                acc[mi][ni] = __builtin_amdgcn_mfma_f32_16x16x32_bf16(
                    af[mi], bfr[ni], acc[mi][ni], 0, 0, 0);
        __syncthreads();
    }

    #pragma unroll
    for (int mi = 0; mi < 4; ++mi) {
        #pragma unroll
        for (int ni = 0; ni < 2; ++ni) {
            const int col = col0 + wn + ni * 16 + l16;
            const float bia = (col < 1024) ? bias0[col] : bias1[col - 1024];
            #pragma unroll
            for (int r = 0; r < 4; ++r) {
                const int row = row0 + wm + mi * 16 + quad * 4 + r;
                C[(size_t)row * N + col] = __float2bfloat16(acc[mi][ni][r] + bia);
            }
        }
    }
}

// ---------------------------------------------------------------------------
// Output projection, split-K=2 (512 blocks), swizzled staging, atomicAdd onto
// bias-initialized out. BM=128, BN=64, BK=32.
// ---------------------------------------------------------------------------
__global__ __launch_bounds__(256)
void gemm_out(const __hip_bfloat16* __restrict__ A,
              const __hip_bfloat16* __restrict__ Bt,
              float* __restrict__ C,
              int M, int N, int K)   // K = full depth (1024)
{
    __shared__ __bf16 As[128 * 32];
    __shared__ __bf16 Bs[64 * 32];

    const int tid  = threadIdx.x;
    const int wave = tid >> 6, lane = tid & 63;
    const int quad = lane >> 4, l16 = lane & 15;
    const int wm = (wave >> 1) * 64;
    const int wn = (wave & 1) * 32;
    const int row0 = blockIdx.y * 128, col0 = blockIdx.x * 64;
    const int kz0 = blockIdx.z * (K / 2), kz1 = kz0 + K / 2;

    const int cr = lane >> 2;
    const int cc = stage_cc(lane);

    const __hip_bfloat16* gsrc[3];
    __bf16* ldst[3];
    #pragma unroll
    for (int i = 0; i < 3; ++i) {
        int c = wave * 3 + i;
        if (c < 8) {
            gsrc[i] = A  + (size_t)(row0 + c * 16 + cr) * K + cc;
            ldst[i] = &As[c * 512];
        } else {
            gsrc[i] = Bt + (size_t)(col0 + (c - 8) * 16 + cr) * K + cc;
            ldst[i] = &Bs[(c - 8) * 512];
        }
    }

    f32x4 acc[4][2] = {};

    for (int k0 = kz0; k0 < kz1; k0 += 32) {
        #pragma unroll
        for (int i = 0; i < 3; ++i)
            glds16(gsrc[i] + k0, ldst[i]);
        __syncthreads();

        bf16x8 af[4], bfr[2];
        #pragma unroll
        for (int mi = 0; mi < 4; ++mi)
            af[mi] = *(const bf16x8*)&As[frag_off(wm + mi * 16 + l16, quad)];
        #pragma unroll
        for (int ni = 0; ni < 2; ++ni)
            bfr[ni] = *(const bf16x8*)&Bs[frag_off(wn + ni * 16 + l16, quad)];

        #pragma unroll
        for (int mi = 0; mi < 4; ++mi)
            #pragma unroll
            for (int ni = 0; ni < 2; ++ni)
                acc[mi][ni] = __builtin_amdgcn_mfma_f32_16x16x32_bf16(
                    af[mi], bfr[ni], acc[mi][ni], 0, 0, 0);
        __syncthreads();
    }

    #pragma unroll
    for (int mi = 0; mi < 4; ++mi) {
        #pragma unroll
        for (int ni = 0; ni < 2; ++ni) {
            const int col = col0 + wn + ni * 16 + l16;
            #pragma unroll
            for (int r = 0; r < 4; ++r) {
                const int row = row0 + wm + mi * 16 + quad * 4 + r;
                atomicAdd(&C[(size_t)row * N + col], acc[mi][ni][r]);
            }
        }
    }
}

// ---------------------------------------------------------------------------
// MFMA flash attention over ragged segments (unchanged, proven).
// ---------------------------------------------------------------------------
#define CH 64

__global__ __launch_bounds__(256)
void attn_mfma(const __hip_bfloat16* __restrict__ qg,
               const __hip_bfloat16* __restrict__ kg,   // kvb
               const __hip_bfloat16* __restrict__ vg,   // kvb + 1024
               const int* __restrict__ seg_q, const int* __restrict__ seg_kv,
               __hip_bfloat16* __restrict__ wv)
{
    const int h = blockIdx.x & 15;
    const int s = blockIdx.x >> 4;

    __shared__ int sb[4];
    __shared__ __bf16 Ks[CH][72];
    __shared__ __bf16 Vt[64][CH + 8];
    __shared__ __bf16 Ps[4][16][CH + 8];

    if (threadIdx.x == 0) {
        int lo, hi;
        lo = 0; hi = TOTAL_Q;
        while (lo < hi) { int m = (lo + hi) >> 1; if (seg_q[m] <  s) lo = m + 1; else hi = m; }
        sb[0] = lo;
        hi = TOTAL_Q;
        while (lo < hi) { int m = (lo + hi) >> 1; if (seg_q[m] <= s) lo = m + 1; else hi = m; }
        sb[1] = lo;
        lo = 0; hi = TOTAL_KV;
        while (lo < hi) { int m = (lo + hi) >> 1; if (seg_kv[m] <  s) lo = m + 1; else hi = m; }
        sb[2] = lo;
        hi = TOTAL_KV;
        while (lo < hi) { int m = (lo + hi) >> 1; if (seg_kv[m] <= s) lo = m + 1; else hi = m; }
        sb[3] = lo;
    }
    __syncthreads();
    const int qbeg = sb[0], qend = sb[1], kbeg = sb[2], kend = sb[3];

    const int tid  = threadIdx.x;
    const int wave = tid >> 6, lane = tid & 63;
    const int quad = lane >> 4, l16 = lane & 15;

    for (int qt = qbeg; qt < qend; qt += 64) {
        const int qrow = qt + wave * 16 + l16;
        const int qrc  = min(qrow, qend - 1);
        bf16x8 qf[2];
        qf[0] = *(const bf16x8*)(qg + (size_t)qrc * DQK + h * 64 + quad * 8);
        qf[1] = *(const bf16x8*)(qg + (size_t)qrc * DQK + h * 64 + 32 + quad * 8);

        float m[4]  = { -1e30f, -1e30f, -1e30f, -1e30f };
        float l[4]  = { 0.f, 0.f, 0.f, 0.f };
        f32x4 acc[4] = {};

        for (int c0 = kbeg; c0 < kend; c0 += CH) {
            const int cl = min(CH, kend - c0);
            __syncthreads();

            #pragma unroll
            for (int it = 0; it < 2; ++it) {
                int e = (it * 256 + tid) * 8;
                int r = e >> 6, d = e & 63;
                bf16x8 z = {};
                if (r < cl)
                    z = *(const bf16x8*)(kg + (size_t)(c0 + r) * KVSTR + h * 64 + d);
                *(bf16x8*)&Ks[r][d] = z;
            }
            #pragma unroll
            for (int it = 0; it < 4; ++it) {
                int e = (it * 256 + tid) * 4;
                int r = e >> 6, d = e & 63;
                __bf16 t0 = 0, t1 = 0, t2 = 0, t3 = 0;
                if (r < cl) {
                    bf16x8 vv;
                    uint2 uu = *(const uint2*)(vg + (size_t)(c0 + r) * KVSTR + h * 64 + d);
                    *(uint2*)&vv = uu;
                    t0 = vv[0]; t1 = vv[1]; t2 = vv[2]; t3 = vv[3];
                }
                Vt[d + 0][r] = t0; Vt[d + 1][r] = t1;
                Vt[d + 2][r] = t2; Vt[d + 3][r] = t3;
            }
            __syncthreads();

            f32x4 sc[4];
            #pragma unroll
            for (int t = 0; t < 4; ++t) {
                bf16x8 b0 = *(const bf16x8*)&Ks[t * 16 + l16][quad * 8];
                bf16x8 b1 = *(const bf16x8*)&Ks[t * 16 + l16][32 + quad * 8];
                f32x4 z = {};
                z = __builtin_amdgcn_mfma_f32_16x16x32_bf16(qf[0], b0, z, 0, 0, 0);
                z = __builtin_amdgcn_mfma_f32_16x16x32_bf16(qf[1], b1, z, 0, 0, 0);
                sc[t] = z;
            }

            float sv[4][4];
            #pragma unroll
            for (int t = 0; t < 4; ++t) {
                const bool ok = (c0 + t * 16 + l16) < kend;
                #pragma unroll
                for (int r = 0; r < 4; ++r)
                    sv[t][r] = ok ? sc[t][r] * SCALER : -1e30f;
            }

            #pragma unroll
            for (int r = 0; r < 4; ++r) {
                float mx = fmaxf(fmaxf(sv[0][r], sv[1][r]), fmaxf(sv[2][r], sv[3][r]));
                mx = fmaxf(mx, __shfl_xor(mx, 1));
                mx = fmaxf(mx, __shfl_xor(mx, 2));
                mx = fmaxf(mx, __shfl_xor(mx, 4));
                mx = fmaxf(mx, __shfl_xor(mx, 8));
                const float mn = fmaxf(m[r], mx);
                const float alpha = __expf(m[r] - mn);
                m[r] = mn;
                float rs = 0.f;
                #pragma unroll
                for (int t = 0; t < 4; ++t) {
                    const float p = __expf(sv[t][r] - mn);
                    sv[t][r] = p;
                    rs += p;
                }
                rs += __shfl_xor(rs, 1);
                rs += __shfl_xor(rs, 2);
                rs += __shfl_xor(rs, 4);
                rs += __shfl_xor(rs, 8);
                l[r] = l[r] * alpha + rs;
                #pragma unroll
                for (int dt = 0; dt < 4; ++dt) acc[dt][r] *= alpha;
            }

            #pragma unroll
            for (int t = 0; t < 4; ++t)
                #pragma unroll
                for (int r = 0; r < 4; ++r)
                    Ps[wave][quad * 4 + r][t * 16 + l16] = (__bf16)sv[t][r];
            __syncthreads();

            #pragma unroll
            for (int ks = 0; ks < 2; ++ks) {
                bf16x8 pa = *(const bf16x8*)&Ps[wave][l16][ks * 32 + quad * 8];
                #pragma unroll
                for (int dt = 0; dt < 4; ++dt) {
                    bf16x8 vbf = *(const bf16x8*)&Vt[dt * 16 + l16][ks * 32 + quad * 8];
                    acc[dt] = __builtin_amdgcn_mfma_f32_16x16x32_bf16(pa, vbf, acc[dt], 0, 0, 0);
                }
            }
        }

        float inv[4];
        #pragma unroll
        for (int r = 0; r < 4; ++r) inv[r] = 1.f / l[r];
        #pragma unroll
        for (int dt = 0; dt < 4; ++dt) {
            #pragma unroll
            for (int r = 0; r < 4; ++r) {
                const int row = qt + wave * 16 + quad * 4 + r;
                if (row < qend)
                    wv[(size_t)row * DV + h * 64 + dt * 16 + l16] =
                        __float2bfloat16(acc[dt][r] * inv[r]);
            }
        }
    }
}

// ---------------------------------------------------------------------------
extern "C" void kernel_launch(void* const* d_in, const int* in_sizes, int n_in,
                              void* d_out, int out_size, void* d_ws, size_t ws_size,
                              hipStream_t stream)
{
    const float* A     = (const float*)d_in[0];
    const float* B0    = (const float*)d_in[1];
    const int*   seg_q = (const int*)  d_in[2];
    const int*   seg_kv= (const int*)  d_in[3];
    const float* Wq    = (const float*)d_in[4];
    const float* bq    = (const float*)d_in[5];
    const float* Wk    = (const float*)d_in[6];
    const float* bk    = (const float*)d_in[7];
    const float* Wv    = (const float*)d_in[8];
    const float* bv    = (const float*)d_in[9];
    const float* Wf    = (const float*)d_in[10];
    const float* bf    = (const float*)d_in[11];
    float* out = (float*)d_out;

    // Workspace (bf16 elems), 29.6 MB total; all offsets 16B-aligned
    __hip_bfloat16* B0bf = (__hip_bfloat16*)d_ws;                 // 2048*1056
    __hip_bfloat16* Wqt  = B0bf + (size_t)TOTAL_KV * KVIN_P;      // 1024*1024
    __hip_bfloat16* Wkt  = Wqt  + (size_t)QIN * DQK;              // 1024*1056  \ fused
    __hip_bfloat16* Wvt  = Wkt  + (size_t)DQK * KVIN_P;           // 1024*1056  / [2048][1056]
    __hip_bfloat16* Wft  = Wvt  + (size_t)DV * KVIN_P;            // 1024*1024
    __hip_bfloat16* Abf  = Wft  + (size_t)DV * QIN;               // 2048*1024
    __hip_bfloat16* qb   = Abf  + (size_t)TOTAL_Q * QIN;          // 2048*1024
    __hip_bfloat16* kvb  = qb   + (size_t)TOTAL_Q * DQK;          // 2048*2048 fused [k|v]
    __hip_bfloat16* wvb  = Abf;  // alias: Abf dead after grouped QKV GEMM

    const dim3 b256(256);

    // 1) fused prep: casts + weight transposes + out-bias init
    prep_k<<<dim3(10368), b256, 0, stream>>>(A, B0, Wq, Wk, Wv, Wf, bf,
                                             Abf, B0bf, Wqt, Wkt, Wvt, Wft, out);

    // 2) grouped Q + KV projections (768 blocks; swizzled LDS)
    gemm_qkv<<<dim3(768), b256, 0, stream>>>(Abf, Wqt, bq, qb,
                                             B0bf, Wkt, bk, bv, kvb);

    // 3) attention: block per (segment, head)
    attn_mfma<<<dim3(32 * 16), b256, 0, stream>>>(qb, kvb, kvb + 1024, seg_q, seg_kv, wvb);

    // 4) output projection, split-K=2, atomic accumulate onto bias-initialized out
    gemm_out<<<dim3(QIN / 64, TOTAL_Q / 128, 2), b256, 0, stream>>>(
        wvb, Wft, out, TOTAL_Q, QIN, DV);
}